// Round 1
// baseline (399.146 us; speedup 1.0000x reference)
//
#include <hip/hip_runtime.h>
#include <stdint.h>

#define NEG9 (-1e9f)

typedef __attribute__((ext_vector_type(8))) short short8;
typedef __attribute__((ext_vector_type(8))) unsigned short ushort8;
typedef __attribute__((ext_vector_type(4))) unsigned short ushort4_t;
typedef __attribute__((ext_vector_type(4))) float f32x4;

#define MFMA_BF16(a,b,c) __builtin_amdgcn_mfma_f32_16x16x32_bf16((a),(b),(c),0,0,0)

__device__ __forceinline__ unsigned short f2bf(float f) {
  union { float f; unsigned int u; } x; x.f = f;
  unsigned int r = x.u + 0x7fffu + ((x.u >> 16) & 1u);
  return (unsigned short)(r >> 16);
}
__device__ __forceinline__ float bf2f(unsigned short h) {
  union { unsigned int u; float f; } x; x.u = ((unsigned int)h) << 16;
  return x.f;
}
__device__ __forceinline__ void gload_lds16(const unsigned short* g, unsigned short* l) {
  __builtin_amdgcn_global_load_lds(
      (const __attribute__((address_space(1))) unsigned int*)g,
      (__attribute__((address_space(3))) unsigned int*)l, 16, 0, 0);
}

// ---------------- fp32 -> bf16 convert ----------------
__global__ void cvt_f32_bf16(const float* __restrict__ in, unsigned short* __restrict__ out, int n4) {
  int i = blockIdx.x * blockDim.x + threadIdx.x;
  int stride = gridDim.x * blockDim.x;
  for (; i < n4; i += stride) {
    float4 v = ((const float4*)in)[i];
    ushort4_t o;
    o.x = f2bf(v.x); o.y = f2bf(v.y); o.z = f2bf(v.z); o.w = f2bf(v.w);
    ((ushort4_t*)out)[i] = o;
  }
}

// ---------------- m97-style GEMM: C[M,N] = A[M,K] * W[N,K]^T + bias ----------------
// A,W bf16 (ushort); out bf16 or fp32. M%128==0, N%128==0, K%32==0.
template<int OUT_F32>
__global__ __launch_bounds__(256)
void gemm_bt(const unsigned short* __restrict__ A,
             const unsigned short* __restrict__ W,
             const float* __restrict__ bias,
             void* __restrict__ Cout,
             int M, int N, int K) {
  __shared__ unsigned short As[128*32];
  __shared__ unsigned short Bs[128*32];
  const int t = threadIdx.x;
  const int lane = t & 63;
  const int wave = t >> 6;
  const int wr = wave >> 1, wc = wave & 1;
  const int lr = lane & 15;
  const int lk = (lane >> 4) << 3;

  const int nbn = N >> 7;
  const int nwg = (M >> 7) * nbn;
  int bid = blockIdx.x;
  if ((nwg & 7) == 0) { int q = nwg >> 3; bid = (bid & 7) * q + (bid >> 3); }
  const int bm = bid / nbn, bn = bid % nbn;

  const long rowA0 = (long)bm * 128;
  const long rowB0 = (long)bn * 128;
  const int srow = t >> 2;
  const int scol = (t & 3) << 3;

  f32x4 acc[4][4];
#pragma unroll
  for (int m = 0; m < 4; m++)
#pragma unroll
    for (int n = 0; n < 4; n++) acc[m][n] = f32x4{0.f,0.f,0.f,0.f};

  for (int k0 = 0; k0 < K; k0 += 32) {
    const unsigned short* ga = A + (rowA0 + srow) * K + k0 + scol;
    const unsigned short* gb = W + (rowB0 + srow) * K + k0 + scol;
    gload_lds16(ga,              As + t*8);
    gload_lds16(ga + (long)64*K, As + t*8 + 2048);
    gload_lds16(gb,              Bs + t*8);
    gload_lds16(gb + (long)64*K, Bs + t*8 + 2048);
    __syncthreads();
    short8 af[4], bf[4];
#pragma unroll
    for (int m = 0; m < 4; m++) af[m] = *(const short8*)&As[(wr*64 + m*16 + lr)*32 + lk];
#pragma unroll
    for (int n = 0; n < 4; n++) bf[n] = *(const short8*)&Bs[(wc*64 + n*16 + lr)*32 + lk];
#pragma unroll
    for (int m = 0; m < 4; m++)
#pragma unroll
      for (int n = 0; n < 4; n++)
        acc[m][n] = MFMA_BF16(af[m], bf[n], acc[m][n]);
    __syncthreads();
  }

  const int rg4 = (lane >> 4) * 4;
#pragma unroll
  for (int m = 0; m < 4; m++) {
#pragma unroll
    for (int n = 0; n < 4; n++) {
      long row = rowA0 + wr*64 + m*16 + rg4;
      long col = rowB0 + wc*64 + n*16 + lr;
      float bv = bias[col];
#pragma unroll
      for (int r = 0; r < 4; r++) {
        float v = acc[m][n][r] + bv;
        if (OUT_F32) ((float*)Cout)[(row + r) * N + col] = v;
        else ((unsigned short*)Cout)[(row + r) * N + col] = f2bf(v);
      }
    }
  }
}

// ---------------- chunk_repr gather + pad to 128 rows, bf16 ----------------
__global__ void repr_pad(const float* __restrict__ hs, unsigned short* __restrict__ out) {
  int r = blockIdx.x;   // 0..127
  int t = threadIdx.x;  // 256
  long base = (long)r * 1024;
  if (r < 64) {
    int b = r >> 5, c = r & 31;
    const float* src = hs + ((long)(b*4096 + c*128 + 127)) * 1024;
#pragma unroll
    for (int j = 0; j < 4; j++) { int idx = t + j*256; out[base + idx] = f2bf(src[idx]); }
  } else {
#pragma unroll
    for (int j = 0; j < 4; j++) out[base + t + j*256] = 0;
  }
}

// ---------------- chunk scores + softmax -> probs [B,H,32,32] fp32 ----------------
__global__ __launch_bounds__(1024) void chunk_probs_k(
    const unsigned short* __restrict__ rb,
    const unsigned short* __restrict__ hb,
    float* __restrict__ probs) {
  __shared__ float rt[32][65];
  __shared__ float ht[32][65];
  int h = blockIdx.x, b = blockIdx.y;
  int t = threadIdx.x;
#pragma unroll
  for (int j = 0; j < 2; j++) {
    int idx = t + j*1024;
    int c = idx >> 6, d = idx & 63;
    rt[c][d] = bf2f(rb[(long)(b*32 + c)*1024 + h*64 + d]);
    ht[c][d] = bf2f(hb[(long)(b*32 + c)*1024 + h*64 + d]);
  }
  __syncthreads();
  int e = t & 31, c = t >> 5;
  float s = 0.f;
#pragma unroll
  for (int d = 0; d < 64; d++) s += rt[c][d] * ht[e][d];
  s *= 0.125f;
  if (e < c) s = NEG9;
  float m = s;
#pragma unroll
  for (int off = 16; off > 0; off >>= 1) m = fmaxf(m, __shfl_xor(m, off, 32));
  float p = __expf(s - m);
  float sum = p;
#pragma unroll
  for (int off = 16; off > 0; off >>= 1) sum += __shfl_xor(sum, off, 32);
  probs[(((long)(b*16 + h))*32 + c)*32 + e] = p / sum;
}

// ---------------- F = K^T V per chunk: f[bid][d][e], bid = b*512+h*32+c ----------------
__global__ __launch_bounds__(256) void f_kernel(
    const unsigned short* __restrict__ Kb, const unsigned short* __restrict__ Vb,
    unsigned short* __restrict__ f) {
  __shared__ unsigned short ks[128*64];
  __shared__ unsigned short vs[128*64];
  int bid = blockIdx.x;
  int c = bid & 31, h = (bid >> 5) & 15, b = bid >> 9;
  int t = threadIdx.x;
  const unsigned short* kg = Kb + ((long)(b*4096 + c*128))*1024 + h*64;
  const unsigned short* vg = Vb + ((long)(b*4096 + c*128))*1024 + h*64;
  int sr = t >> 3, sc = (t & 7) << 3;
#pragma unroll
  for (int i = 0; i < 4; i++) {
    gload_lds16(kg + (long)(sr + i*32)*1024 + sc, ks + t*8 + i*2048);
    gload_lds16(vg + (long)(sr + i*32)*1024 + sc, vs + t*8 + i*2048);
  }
  __syncthreads();
  int d0 = (t & 15) << 2, e0 = (t >> 4) << 2;
  float acc[4][4] = {};
  for (int s = 0; s < 128; s++) {
    float kv[4], vv[4];
#pragma unroll
    for (int i = 0; i < 4; i++) kv[i] = bf2f(ks[s*64 + d0 + i]);
#pragma unroll
    for (int i = 0; i < 4; i++) vv[i] = bf2f(vs[s*64 + e0 + i]);
#pragma unroll
    for (int i = 0; i < 4; i++)
#pragma unroll
      for (int j = 0; j < 4; j++) acc[i][j] += kv[i] * vv[j];
  }
  unsigned short* fo = f + (long)bid * 4096;
#pragma unroll
  for (int i = 0; i < 4; i++)
#pragma unroll
    for (int j = 0; j < 4; j++) fo[(d0 + i)*64 + e0 + j] = f2bf(acc[i][j]);
}

// ---------------- retrieved^T per chunk: retT[bid][e][d] = sum_ec probs[ec] f[ec][d][e] ----------------
__global__ __launch_bounds__(256) void retrieve_k(
    const float* __restrict__ probs, const unsigned short* __restrict__ f,
    unsigned short* __restrict__ retT) {
  __shared__ float pr[32];
  int bid = blockIdx.x;
  int c = bid & 31;
  int bh = bid >> 5;
  int t = threadIdx.x;
  if (t < 32) pr[t] = probs[((long)(bh*32 + c))*32 + t];
  __syncthreads();
  int e = t >> 2, d0 = (t & 3) << 4;
  float acc[16] = {};
  const unsigned short* fb = f + (long)bh * 32 * 4096;
  for (int ec = c; ec < 32; ec++) {  // probs exactly 0 for ec<c
    float p = pr[ec];
    const unsigned short* fe = fb + (long)ec*4096 + d0*64 + e;
#pragma unroll
    for (int j = 0; j < 16; j++) acc[j] += p * bf2f(fe[j*64]);
  }
  unsigned short* ro = retT + (long)bid*4096 + e*64 + d0;
  ushort8 w0, w1;
#pragma unroll
  for (int j = 0; j < 8; j++) { w0[j] = f2bf(acc[j]); w1[j] = f2bf(acc[8 + j]); }
  *(ushort8*)ro = w0;
  *(ushort8*)(ro + 8) = w1;
}

// ---------------- fused attention per (b,h,c): long_term + local, out bf16 [B*S, D] ----------------
__global__ __launch_bounds__(256) void attn_k(
    const unsigned short* __restrict__ Qb,
    const unsigned short* __restrict__ Kb,
    const unsigned short* __restrict__ Vb,
    const unsigned short* __restrict__ retT,
    unsigned short* __restrict__ attn) {
  __shared__ unsigned short ks[128*64];   // [t][d] linear
  __shared__ unsigned short vT[64*136];   // [e][t] padded
  __shared__ unsigned short rT[64*64];    // [e'][d] linear
  __shared__ unsigned short P[128*136];   // [s][t] padded
  const int bid = blockIdx.x;
  const int c = bid & 31, h = (bid >> 5) & 15, b = bid >> 9;
  const int t = threadIdx.x;
  const int lane = t & 63, w = t >> 6;
  const int lr = lane & 15, lk = (lane >> 4) << 3;
  const int rg4 = (lane >> 4) * 4;

  const long rowbase = (long)(b*4096 + c*128);
  const unsigned short* kg = Kb + rowbase*1024 + h*64;
  const unsigned short* vg = Vb + rowbase*1024 + h*64;
  const unsigned short* qg = Qb + rowbase*1024 + h*64;
  const unsigned short* rtg = retT + (long)bid*4096;

  {
    int sr = t >> 3, scc = (t & 7) << 3;
#pragma unroll
    for (int i = 0; i < 4; i++)
      gload_lds16(kg + (long)(sr + i*32)*1024 + scc, ks + t*8 + i*2048);
#pragma unroll
    for (int i = 0; i < 2; i++)
      gload_lds16(rtg + (t + i*256)*8, rT + (t + i*256)*8);
  }
  {
    int s = t >> 1, e0 = (t & 1) << 5;
#pragma unroll
    for (int jj = 0; jj < 4; jj++) {
      ushort8 v = *(const ushort8*)&vg[(long)s*1024 + e0 + jj*8];
#pragma unroll
      for (int x = 0; x < 8; x++) vT[(e0 + jj*8 + x)*136 + s] = v[x];
    }
  }
  __syncthreads();

  // QK^T: rows w*32..w*32+31, all 128 cols
  short8 qa[2][2];
#pragma unroll
  for (int m = 0; m < 2; m++)
#pragma unroll
    for (int kk = 0; kk < 2; kk++)
      qa[m][kk] = *(const short8*)&qg[(long)(w*32 + m*16 + lr)*1024 + kk*32 + lk];
  f32x4 scf[2][8];
#pragma unroll
  for (int m = 0; m < 2; m++)
#pragma unroll
    for (int n = 0; n < 8; n++) scf[m][n] = f32x4{0.f,0.f,0.f,0.f};
#pragma unroll
  for (int n = 0; n < 8; n++) {
#pragma unroll
    for (int kk = 0; kk < 2; kk++) {
      short8 kf = *(const short8*)&ks[(n*16 + lr)*64 + kk*32 + lk];
#pragma unroll
      for (int m = 0; m < 2; m++) scf[m][n] = MFMA_BF16(qa[m][kk], kf, scf[m][n]);
    }
  }

  // masked softmax per row; write P (bf16) to LDS
  float rsum[2][4];
#pragma unroll
  for (int m = 0; m < 2; m++) {
#pragma unroll
    for (int r = 0; r < 4; r++) {
      int srow = w*32 + m*16 + rg4 + r;
      float vals[8];
      float mx = -1e30f;
#pragma unroll
      for (int n = 0; n < 8; n++) {
        int tcol = n*16 + lr;
        float v_ = scf[m][n][r] * 0.125f;
        if (tcol < srow) v_ = NEG9;
        vals[n] = v_;
        mx = fmaxf(mx, v_);
      }
#pragma unroll
      for (int off = 1; off < 16; off <<= 1) mx = fmaxf(mx, __shfl_xor(mx, off, 16));
      float sum = 0.f;
#pragma unroll
      for (int n = 0; n < 8; n++) {
        float p = __expf(vals[n] - mx);
        sum += p;
        P[srow*136 + n*16 + lr] = f2bf(p);
      }
#pragma unroll
      for (int off = 1; off < 16; off <<= 1) sum += __shfl_xor(sum, off, 16);
      rsum[m][r] = sum;
    }
  }

  // long_term: qa @ rT  (reuses qa)
  f32x4 outa[2][4];
#pragma unroll
  for (int m = 0; m < 2; m++)
#pragma unroll
    for (int n = 0; n < 4; n++) outa[m][n] = f32x4{0.f,0.f,0.f,0.f};
#pragma unroll
  for (int n = 0; n < 4; n++) {
#pragma unroll
    for (int kk = 0; kk < 2; kk++) {
      short8 rf = *(const short8*)&rT[(n*16 + lr)*64 + kk*32 + lk];
#pragma unroll
      for (int m = 0; m < 2; m++) outa[m][n] = MFMA_BF16(qa[m][kk], rf, outa[m][n]);
    }
  }

  // PV: P rows w*32.. (written by this wave) @ vT
  f32x4 pv[2][4];
#pragma unroll
  for (int m = 0; m < 2; m++)
#pragma unroll
    for (int n = 0; n < 4; n++) pv[m][n] = f32x4{0.f,0.f,0.f,0.f};
#pragma unroll
  for (int kk = 0; kk < 4; kk++) {
    short8 pa[2];
#pragma unroll
    for (int m = 0; m < 2; m++) pa[m] = *(const short8*)&P[(w*32 + m*16 + lr)*136 + kk*32 + lk];
#pragma unroll
    for (int n = 0; n < 4; n++) {
      short8 vf = *(const short8*)&vT[(n*16 + lr)*136 + kk*32 + lk];
#pragma unroll
      for (int m = 0; m < 2; m++) pv[m][n] = MFMA_BF16(pa[m], vf, pv[m][n]);
    }
  }

  unsigned short* ao = attn + rowbase*1024 + h*64;
#pragma unroll
  for (int m = 0; m < 2; m++)
#pragma unroll
    for (int n = 0; n < 4; n++)
#pragma unroll
      for (int r = 0; r < 4; r++) {
        int srow = w*32 + m*16 + rg4 + r;
        float v_ = pv[m][n][r] / rsum[m][r] + outa[m][n][r];
        ao[(long)srow*1024 + n*16 + lr] = f2bf(v_);
      }
}

// ---------------- launch ----------------
extern "C" void kernel_launch(void* const* d_in, const int* in_sizes, int n_in,
                              void* d_out, int out_size, void* d_ws, size_t ws_size,
                              hipStream_t stream) {
  const float* hs = (const float*)d_in[0];
  const float* Wq = (const float*)d_in[1];
  const float* bq = (const float*)d_in[2];
  const float* Wk = (const float*)d_in[3];
  const float* bk = (const float*)d_in[4];
  const float* Wv = (const float*)d_in[5];
  const float* bv = (const float*)d_in[6];
  const float* Wo = (const float*)d_in[7];
  const float* bo = (const float*)d_in[8];
  const float* Wr = (const float*)d_in[9];
  const float* br = (const float*)d_in[10];
  const float* Wh = (const float*)d_in[11];
  const float* bh = (const float*)d_in[12];

  char* p = (char*)d_ws;
  unsigned short* hsb  = (unsigned short*)p; p += (size_t)8192*1024*2;
  unsigned short* Wqb  = (unsigned short*)p; p += (size_t)1024*1024*2;
  unsigned short* Wkb  = (unsigned short*)p; p += (size_t)1024*1024*2;
  unsigned short* Wvb  = (unsigned short*)p; p += (size_t)1024*1024*2;
  unsigned short* Wob  = (unsigned short*)p; p += (size_t)1024*1024*2;
  unsigned short* Wrb  = (unsigned short*)p; p += (size_t)1024*1024*2;
  unsigned short* Whb  = (unsigned short*)p; p += (size_t)1024*1024*2;
  unsigned short* Qb   = (unsigned short*)p; p += (size_t)8192*1024*2;
  unsigned short* Kb   = (unsigned short*)p; p += (size_t)8192*1024*2;
  unsigned short* Vb   = (unsigned short*)p; p += (size_t)8192*1024*2;
  unsigned short* reprb= (unsigned short*)p; p += (size_t)128*1024*2;
  unsigned short* rb   = (unsigned short*)p; p += (size_t)128*1024*2;
  unsigned short* hb   = (unsigned short*)p; p += (size_t)128*1024*2;
  float*          probs= (float*)p;          p += (size_t)2*16*32*32*4;
  unsigned short* fbuf = (unsigned short*)p; p += (size_t)2*16*32*4096*2;
  unsigned short* retT = (unsigned short*)p; p += (size_t)2*16*32*4096*2;
  unsigned short* attnb = hsb;  // overlay: hsb dead after QKV+r/h GEMMs

  // converts
  cvt_f32_bf16<<<8192, 256, 0, stream>>>(hs, hsb, 2097152);
  cvt_f32_bf16<<<1024, 256, 0, stream>>>(Wq, Wqb, 262144);
  cvt_f32_bf16<<<1024, 256, 0, stream>>>(Wk, Wkb, 262144);
  cvt_f32_bf16<<<1024, 256, 0, stream>>>(Wv, Wvb, 262144);
  cvt_f32_bf16<<<1024, 256, 0, stream>>>(Wo, Wob, 262144);
  cvt_f32_bf16<<<1024, 256, 0, stream>>>(Wr, Wrb, 262144);
  cvt_f32_bf16<<<1024, 256, 0, stream>>>(Wh, Whb, 262144);

  // projections
  gemm_bt<0><<<512, 256, 0, stream>>>(hsb, Wqb, bq, Qb, 8192, 1024, 1024);
  gemm_bt<0><<<512, 256, 0, stream>>>(hsb, Wkb, bk, Kb, 8192, 1024, 1024);
  gemm_bt<0><<<512, 256, 0, stream>>>(hsb, Wvb, bv, Vb, 8192, 1024, 1024);

  // chunk repr + r/h projections (M padded to 128)
  repr_pad<<<128, 256, 0, stream>>>(hs, reprb);
  gemm_bt<0><<<8, 256, 0, stream>>>(reprb, Wrb, br, rb, 128, 1024, 1024);
  gemm_bt<0><<<8, 256, 0, stream>>>(reprb, Whb, bh, hb, 128, 1024, 1024);

  // chunk probs
  chunk_probs_k<<<dim3(16, 2), 1024, 0, stream>>>(rb, hb, probs);

  // F = K^T V per chunk
  f_kernel<<<1024, 256, 0, stream>>>(Kb, Vb, fbuf);

  // retrieved^T
  retrieve_k<<<1024, 256, 0, stream>>>(probs, fbuf, retT);

  // fused long-term + local attention
  attn_k<<<1024, 256, 0, stream>>>(Qb, Kb, Vb, retT, attnb);

  // output projection (fp32 out)
  gemm_bt<1><<<512, 256, 0, stream>>>(attnb, Wob, bo, d_out, 8192, 1024, 1024);
}

// Round 2
// 333.664 us; speedup vs baseline: 1.1963x; 1.1963x over previous
//
#include <hip/hip_runtime.h>
#include <stdint.h>

#define NEG9 (-1e9f)

typedef __attribute__((ext_vector_type(8))) short short8;
typedef __attribute__((ext_vector_type(8))) unsigned short ushort8;
typedef __attribute__((ext_vector_type(4))) unsigned short ushort4_t;
typedef __attribute__((ext_vector_type(4))) float f32x4;

#define MFMA_BF16(a,b,c) __builtin_amdgcn_mfma_f32_16x16x32_bf16((a),(b),(c),0,0,0)

__device__ __forceinline__ unsigned short f2bf(float f) {
  union { float f; unsigned int u; } x; x.f = f;
  unsigned int r = x.u + 0x7fffu + ((x.u >> 16) & 1u);
  return (unsigned short)(r >> 16);
}
__device__ __forceinline__ float bf2f(unsigned short h) {
  union { unsigned int u; float f; } x; x.u = ((unsigned int)h) << 16;
  return x.f;
}
__device__ __forceinline__ void gload_lds16(const unsigned short* g, unsigned short* l) {
  __builtin_amdgcn_global_load_lds(
      (const __attribute__((address_space(1))) unsigned int*)g,
      (__attribute__((address_space(3))) unsigned int*)l, 16, 0, 0);
}

// ---------------- fp32 -> bf16 convert ----------------
__global__ void cvt_f32_bf16(const float* __restrict__ in, unsigned short* __restrict__ out, int n4) {
  int i = blockIdx.x * blockDim.x + threadIdx.x;
  int stride = gridDim.x * blockDim.x;
  for (; i < n4; i += stride) {
    float4 v = ((const float4*)in)[i];
    ushort4_t o;
    o.x = f2bf(v.x); o.y = f2bf(v.y); o.z = f2bf(v.z); o.w = f2bf(v.w);
    ((ushort4_t*)out)[i] = o;
  }
}

// 6 weight matrices in one dispatch (blockIdx.y selects)
__global__ void cvt_w6(const float* a0, const float* a1, const float* a2,
                       const float* a3, const float* a4, const float* a5,
                       unsigned short* b0, unsigned short* b1, unsigned short* b2,
                       unsigned short* b3, unsigned short* b4, unsigned short* b5) {
  const float* in; unsigned short* out;
  switch (blockIdx.y) {
    case 0: in = a0; out = b0; break;
    case 1: in = a1; out = b1; break;
    case 2: in = a2; out = b2; break;
    case 3: in = a3; out = b3; break;
    case 4: in = a4; out = b4; break;
    default: in = a5; out = b5; break;
  }
  const int n4 = 262144;
  int i = blockIdx.x * blockDim.x + threadIdx.x;
  int stride = gridDim.x * blockDim.x;
  for (; i < n4; i += stride) {
    float4 v = ((const float4*)in)[i];
    ushort4_t o;
    o.x = f2bf(v.x); o.y = f2bf(v.y); o.z = f2bf(v.z); o.w = f2bf(v.w);
    ((ushort4_t*)out)[i] = o;
  }
}

// ---------------- m97-style GEMM: C[M,N] = A[M,K] * W[N,K]^T + bias ----------------
template<int OUT_F32>
__global__ __launch_bounds__(256)
void gemm_bt(const unsigned short* __restrict__ A,
             const unsigned short* __restrict__ W,
             const float* __restrict__ bias,
             void* __restrict__ Cout,
             int M, int N, int K) {
  __shared__ unsigned short As[128*32];
  __shared__ unsigned short Bs[128*32];
  const int t = threadIdx.x;
  const int lane = t & 63;
  const int wave = t >> 6;
  const int wr = wave >> 1, wc = wave & 1;
  const int lr = lane & 15;
  const int lk = (lane >> 4) << 3;

  const int nbn = N >> 7;
  const int nwg = (M >> 7) * nbn;
  int bid = blockIdx.x;
  if ((nwg & 7) == 0) { int q = nwg >> 3; bid = (bid & 7) * q + (bid >> 3); }
  const int bm = bid / nbn, bn = bid % nbn;

  const long rowA0 = (long)bm * 128;
  const long rowB0 = (long)bn * 128;
  const int srow = t >> 2;
  const int scol = (t & 3) << 3;

  f32x4 acc[4][4];
#pragma unroll
  for (int m = 0; m < 4; m++)
#pragma unroll
    for (int n = 0; n < 4; n++) acc[m][n] = f32x4{0.f,0.f,0.f,0.f};

  for (int k0 = 0; k0 < K; k0 += 32) {
    const unsigned short* ga = A + (rowA0 + srow) * K + k0 + scol;
    const unsigned short* gb = W + (rowB0 + srow) * K + k0 + scol;
    gload_lds16(ga,              As + t*8);
    gload_lds16(ga + (long)64*K, As + t*8 + 2048);
    gload_lds16(gb,              Bs + t*8);
    gload_lds16(gb + (long)64*K, Bs + t*8 + 2048);
    __syncthreads();
    short8 af[4], bf[4];
#pragma unroll
    for (int m = 0; m < 4; m++) af[m] = *(const short8*)&As[(wr*64 + m*16 + lr)*32 + lk];
#pragma unroll
    for (int n = 0; n < 4; n++) bf[n] = *(const short8*)&Bs[(wc*64 + n*16 + lr)*32 + lk];
#pragma unroll
    for (int m = 0; m < 4; m++)
#pragma unroll
      for (int n = 0; n < 4; n++)
        acc[m][n] = MFMA_BF16(af[m], bf[n], acc[m][n]);
    __syncthreads();
  }

  const int rg4 = (lane >> 4) * 4;
#pragma unroll
  for (int m = 0; m < 4; m++) {
#pragma unroll
    for (int n = 0; n < 4; n++) {
      long row = rowA0 + wr*64 + m*16 + rg4;
      long col = rowB0 + wc*64 + n*16 + lr;
      float bv = bias[col];
#pragma unroll
      for (int r = 0; r < 4; r++) {
        float v = acc[m][n][r] + bv;
        if (OUT_F32) ((float*)Cout)[(row + r) * N + col] = v;
        else ((unsigned short*)Cout)[(row + r) * N + col] = f2bf(v);
      }
    }
  }
}

// ---------------- chunk_repr gather + pad to 128 rows, bf16 ----------------
__global__ void repr_pad(const float* __restrict__ hs, unsigned short* __restrict__ out) {
  int r = blockIdx.x;   // 0..127
  int t = threadIdx.x;  // 256
  long base = (long)r * 1024;
  if (r < 64) {
    int b = r >> 5, c = r & 31;
    const float* src = hs + ((long)(b*4096 + c*128 + 127)) * 1024;
#pragma unroll
    for (int j = 0; j < 4; j++) { int idx = t + j*256; out[base + idx] = f2bf(src[idx]); }
  } else {
#pragma unroll
    for (int j = 0; j < 4; j++) out[base + t + j*256] = 0;
  }
}

// ---------------- chunk scores + softmax -> probs [B,H,32,32] fp32 ----------------
__global__ __launch_bounds__(1024) void chunk_probs_k(
    const unsigned short* __restrict__ rb,
    const unsigned short* __restrict__ hb,
    float* __restrict__ probs) {
  __shared__ float rt[32][65];
  __shared__ float ht[32][65];
  int h = blockIdx.x, b = blockIdx.y;
  int t = threadIdx.x;
#pragma unroll
  for (int j = 0; j < 2; j++) {
    int idx = t + j*1024;
    int c = idx >> 6, d = idx & 63;
    rt[c][d] = bf2f(rb[(long)(b*32 + c)*1024 + h*64 + d]);
    ht[c][d] = bf2f(hb[(long)(b*32 + c)*1024 + h*64 + d]);
  }
  __syncthreads();
  int e = t & 31, c = t >> 5;
  float s = 0.f;
#pragma unroll
  for (int d = 0; d < 64; d++) s += rt[c][d] * ht[e][d];
  s *= 0.125f;
  if (e < c) s = NEG9;
  float m = s;
#pragma unroll
  for (int off = 16; off > 0; off >>= 1) m = fmaxf(m, __shfl_xor(m, off, 32));
  float p = __expf(s - m);
  float sum = p;
#pragma unroll
  for (int off = 16; off > 0; off >>= 1) sum += __shfl_xor(sum, off, 32);
  probs[(((long)(b*16 + h))*32 + c)*32 + e] = p / sum;
}

// ---------------- F^T = V^T K per chunk via MFMA: fbuf[bid][e*64+d] = sum_s V[s][e] K[s][d] ----------------
__global__ __launch_bounds__(256) void f_kernel(
    const unsigned short* __restrict__ Kb, const unsigned short* __restrict__ Vb,
    unsigned short* __restrict__ f) {
  __shared__ unsigned short vT[64*136];   // [e][s] padded
  __shared__ unsigned short kT[64*136];   // [d][s] padded
  int bid = blockIdx.x;
  int c = bid & 31, h = (bid >> 5) & 15, b = bid >> 9;
  int t = threadIdx.x;
  const unsigned short* kg = Kb + ((long)(b*4096 + c*128))*1024 + h*64;
  const unsigned short* vg = Vb + ((long)(b*4096 + c*128))*1024 + h*64;
  {
    int s = t >> 1, e0 = (t & 1) << 5;
#pragma unroll
    for (int j = 0; j < 4; j++) {
      ushort8 v = *(const ushort8*)&vg[(long)s*1024 + e0 + j*8];
      ushort8 k = *(const ushort8*)&kg[(long)s*1024 + e0 + j*8];
#pragma unroll
      for (int x = 0; x < 8; x++) {
        vT[(e0 + j*8 + x)*136 + s] = v[x];
        kT[(e0 + j*8 + x)*136 + s] = k[x];
      }
    }
  }
  __syncthreads();
  const int lane = t & 63, w = t >> 6;
  const int lr = lane & 15, lk = (lane >> 4) << 3;
  const int rg4 = (lane >> 4) * 4;
  const int e0w = (w & 1) * 32, d0w = (w >> 1) * 32;

  f32x4 acc[2][2];
#pragma unroll
  for (int m = 0; m < 2; m++)
#pragma unroll
    for (int n = 0; n < 2; n++) acc[m][n] = f32x4{0.f,0.f,0.f,0.f};
#pragma unroll
  for (int kk = 0; kk < 4; kk++) {
    short8 af[2], bf[2];
#pragma unroll
    for (int m = 0; m < 2; m++) af[m] = *(const short8*)&vT[(e0w + m*16 + lr)*136 + kk*32 + lk];
#pragma unroll
    for (int n = 0; n < 2; n++) bf[n] = *(const short8*)&kT[(d0w + n*16 + lr)*136 + kk*32 + lk];
#pragma unroll
    for (int m = 0; m < 2; m++)
#pragma unroll
      for (int n = 0; n < 2; n++) acc[m][n] = MFMA_BF16(af[m], bf[n], acc[m][n]);
  }
  unsigned short* fo = f + (long)bid * 4096;
#pragma unroll
  for (int m = 0; m < 2; m++)
#pragma unroll
    for (int n = 0; n < 2; n++)
#pragma unroll
      for (int r = 0; r < 4; r++)
        fo[(e0w + m*16 + rg4 + r)*64 + d0w + n*16 + lr] = f2bf(acc[m][n][r]);
}

// ---------------- retrieved^T: retT[bh,c][x] = sum_ec probs[bh,c,ec] fbuf[bh,ec][x], x=e*64+d ----------------
__global__ __launch_bounds__(256) void retrieve_k(
    const float* __restrict__ probs, const unsigned short* __restrict__ f,
    unsigned short* __restrict__ retT) {
  __shared__ float PL[1024];
  int bh = blockIdx.x;   // 0..31
  int xt = blockIdx.y;   // 0..7
  int t = threadIdx.x;   // 256
  *(float4*)&PL[t*4] = *(const float4*)&probs[(long)bh*1024 + t*4];
  __syncthreads();
  const unsigned int* fb = (const unsigned int*)(f + (long)bh*32*4096);
  const int xo = xt*256 + t;           // uint index within 2048 (= 4096 bf16)
  unsigned int fv[32];
#pragma unroll
  for (int ec = 0; ec < 32; ec++) fv[ec] = fb[ec*2048 + xo];
  unsigned int* ro = (unsigned int*)retT + (long)bh*32*2048 + xo;
  for (int c = 0; c < 32; c++) {
    float a0 = 0.f, a1 = 0.f;
#pragma unroll
    for (int e4 = 0; e4 < 8; e4++) {
      float4 p = *(const float4*)&PL[c*32 + e4*4];
#pragma unroll
      for (int j = 0; j < 4; j++) {
        unsigned int v = fv[e4*4 + j];
        union { unsigned int u; float ff; } lo, hi;
        lo.u = v << 16; hi.u = v & 0xffff0000u;
        a0 += p[j] * lo.ff;
        a1 += p[j] * hi.ff;
      }
    }
    ro[(long)c*2048] = (unsigned int)f2bf(a0) | ((unsigned int)f2bf(a1) << 16);
  }
}

// ---------------- fused attention per (b,h,c): long_term + local, out bf16 [B*S, D] ----------------
__global__ __launch_bounds__(256) void attn_k(
    const unsigned short* __restrict__ Qb,
    const unsigned short* __restrict__ Kb,
    const unsigned short* __restrict__ Vb,
    const unsigned short* __restrict__ retT,
    unsigned short* __restrict__ attn) {
  __shared__ unsigned short ks[128*64];   // [t][d] linear
  __shared__ unsigned short vT[64*136];   // [e][t] padded
  __shared__ unsigned short rT[64*64];    // [e'][d] linear
  __shared__ unsigned short P[128*136];   // [s][t] padded
  const int bid = blockIdx.x;
  const int c = bid & 31, h = (bid >> 5) & 15, b = bid >> 9;
  const int t = threadIdx.x;
  const int lane = t & 63, w = t >> 6;
  const int lr = lane & 15, lk = (lane >> 4) << 3;
  const int rg4 = (lane >> 4) * 4;

  const long rowbase = (long)(b*4096 + c*128);
  const unsigned short* kg = Kb + rowbase*1024 + h*64;
  const unsigned short* vg = Vb + rowbase*1024 + h*64;
  const unsigned short* qg = Qb + rowbase*1024 + h*64;
  const unsigned short* rtg = retT + (long)bid*4096;

  {
    int sr = t >> 3, scc = (t & 7) << 3;
#pragma unroll
    for (int i = 0; i < 4; i++)
      gload_lds16(kg + (long)(sr + i*32)*1024 + scc, ks + t*8 + i*2048);
#pragma unroll
    for (int i = 0; i < 2; i++)
      gload_lds16(rtg + (t + i*256)*8, rT + (t + i*256)*8);
  }
  {
    int s = t >> 1, e0 = (t & 1) << 5;
#pragma unroll
    for (int jj = 0; jj < 4; jj++) {
      ushort8 v = *(const ushort8*)&vg[(long)s*1024 + e0 + jj*8];
#pragma unroll
      for (int x = 0; x < 8; x++) vT[(e0 + jj*8 + x)*136 + s] = v[x];
    }
  }
  __syncthreads();

  // QK^T: rows w*32..w*32+31, all 128 cols
  short8 qa[2][2];
#pragma unroll
  for (int m = 0; m < 2; m++)
#pragma unroll
    for (int kk = 0; kk < 2; kk++)
      qa[m][kk] = *(const short8*)&qg[(long)(w*32 + m*16 + lr)*1024 + kk*32 + lk];
  f32x4 scf[2][8];
#pragma unroll
  for (int m = 0; m < 2; m++)
#pragma unroll
    for (int n = 0; n < 8; n++) scf[m][n] = f32x4{0.f,0.f,0.f,0.f};
#pragma unroll
  for (int n = 0; n < 8; n++) {
#pragma unroll
    for (int kk = 0; kk < 2; kk++) {
      short8 kf = *(const short8*)&ks[(n*16 + lr)*64 + kk*32 + lk];
#pragma unroll
      for (int m = 0; m < 2; m++) scf[m][n] = MFMA_BF16(qa[m][kk], kf, scf[m][n]);
    }
  }

  // masked softmax per row; write P (bf16) to LDS
  float rsum[2][4];
#pragma unroll
  for (int m = 0; m < 2; m++) {
#pragma unroll
    for (int r = 0; r < 4; r++) {
      int srow = w*32 + m*16 + rg4 + r;
      float vals[8];
      float mx = -1e30f;
#pragma unroll
      for (int n = 0; n < 8; n++) {
        int tcol = n*16 + lr;
        float v_ = scf[m][n][r] * 0.125f;
        if (tcol < srow) v_ = NEG9;
        vals[n] = v_;
        mx = fmaxf(mx, v_);
      }
#pragma unroll
      for (int off = 1; off < 16; off <<= 1) mx = fmaxf(mx, __shfl_xor(mx, off, 16));
      float sum = 0.f;
#pragma unroll
      for (int n = 0; n < 8; n++) {
        float p = __expf(vals[n] - mx);
        sum += p;
        P[srow*136 + n*16 + lr] = f2bf(p);
      }
#pragma unroll
      for (int off = 1; off < 16; off <<= 1) sum += __shfl_xor(sum, off, 16);
      rsum[m][r] = sum;
    }
  }

  // long_term: qa @ rT
  f32x4 outa[2][4];
#pragma unroll
  for (int m = 0; m < 2; m++)
#pragma unroll
    for (int n = 0; n < 4; n++) outa[m][n] = f32x4{0.f,0.f,0.f,0.f};
#pragma unroll
  for (int n = 0; n < 4; n++) {
#pragma unroll
    for (int kk = 0; kk < 2; kk++) {
      short8 rf = *(const short8*)&rT[(n*16 + lr)*64 + kk*32 + lk];
#pragma unroll
      for (int m = 0; m < 2; m++) outa[m][n] = MFMA_BF16(qa[m][kk], rf, outa[m][n]);
    }
  }

  // PV: P rows w*32.. (written by this wave) @ vT
  f32x4 pv[2][4];
#pragma unroll
  for (int m = 0; m < 2; m++)
#pragma unroll
    for (int n = 0; n < 4; n++) pv[m][n] = f32x4{0.f,0.f,0.f,0.f};
#pragma unroll
  for (int kk = 0; kk < 4; kk++) {
    short8 pa[2];
#pragma unroll
    for (int m = 0; m < 2; m++) pa[m] = *(const short8*)&P[(w*32 + m*16 + lr)*136 + kk*32 + lk];
#pragma unroll
    for (int n = 0; n < 4; n++) {
      short8 vf = *(const short8*)&vT[(n*16 + lr)*136 + kk*32 + lk];
#pragma unroll
      for (int m = 0; m < 2; m++) pv[m][n] = MFMA_BF16(pa[m], vf, pv[m][n]);
    }
  }

  unsigned short* ao = attn + rowbase*1024 + h*64;
#pragma unroll
  for (int m = 0; m < 2; m++)
#pragma unroll
    for (int n = 0; n < 4; n++)
#pragma unroll
      for (int r = 0; r < 4; r++) {
        int srow = w*32 + m*16 + rg4 + r;
        float v_ = pv[m][n][r] / rsum[m][r] + outa[m][n][r];
        ao[(long)srow*1024 + n*16 + lr] = f2bf(v_);
      }
}

// ---------------- launch ----------------
extern "C" void kernel_launch(void* const* d_in, const int* in_sizes, int n_in,
                              void* d_out, int out_size, void* d_ws, size_t ws_size,
                              hipStream_t stream) {
  const float* hs = (const float*)d_in[0];
  const float* Wq = (const float*)d_in[1];
  const float* bq = (const float*)d_in[2];
  const float* Wk = (const float*)d_in[3];
  const float* bk = (const float*)d_in[4];
  const float* Wv = (const float*)d_in[5];
  const float* bv = (const float*)d_in[6];
  const float* Wo = (const float*)d_in[7];
  const float* bo = (const float*)d_in[8];
  const float* Wr = (const float*)d_in[9];
  const float* br = (const float*)d_in[10];
  const float* Wh = (const float*)d_in[11];
  const float* bh = (const float*)d_in[12];

  char* p = (char*)d_ws;
  unsigned short* hsb  = (unsigned short*)p; p += (size_t)8192*1024*2;
  unsigned short* Wqb  = (unsigned short*)p; p += (size_t)1024*1024*2;
  unsigned short* Wkb  = (unsigned short*)p; p += (size_t)1024*1024*2;
  unsigned short* Wvb  = (unsigned short*)p; p += (size_t)1024*1024*2;
  unsigned short* Wob  = (unsigned short*)p; p += (size_t)1024*1024*2;
  unsigned short* Wrb  = (unsigned short*)p; p += (size_t)1024*1024*2;
  unsigned short* Whb  = (unsigned short*)p; p += (size_t)1024*1024*2;
  unsigned short* Qb   = (unsigned short*)p; p += (size_t)8192*1024*2;
  unsigned short* Kb   = (unsigned short*)p; p += (size_t)8192*1024*2;
  unsigned short* Vb   = (unsigned short*)p; p += (size_t)8192*1024*2;
  unsigned short* reprb= (unsigned short*)p; p += (size_t)128*1024*2;
  unsigned short* rb   = (unsigned short*)p; p += (size_t)128*1024*2;
  unsigned short* hb   = (unsigned short*)p; p += (size_t)128*1024*2;
  float*          probs= (float*)p;          p += (size_t)2*16*32*32*4;
  unsigned short* fbuf = (unsigned short*)p; p += (size_t)2*16*32*4096*2;
  unsigned short* retT = (unsigned short*)p; p += (size_t)2*16*32*4096*2;
  unsigned short* attnb = hsb;  // overlay: hsb dead after QKV+r/h GEMMs

  // converts
  cvt_f32_bf16<<<8192, 256, 0, stream>>>(hs, hsb, 2097152);
  cvt_w6<<<dim3(256, 6), 256, 0, stream>>>(Wq, Wk, Wv, Wo, Wr, Wh,
                                           Wqb, Wkb, Wvb, Wob, Wrb, Whb);

  // projections
  gemm_bt<0><<<512, 256, 0, stream>>>(hsb, Wqb, bq, Qb, 8192, 1024, 1024);
  gemm_bt<0><<<512, 256, 0, stream>>>(hsb, Wkb, bk, Kb, 8192, 1024, 1024);
  gemm_bt<0><<<512, 256, 0, stream>>>(hsb, Wvb, bv, Vb, 8192, 1024, 1024);

  // chunk repr + r/h projections (M padded to 128)
  repr_pad<<<128, 256, 0, stream>>>(hs, reprb);
  gemm_bt<0><<<8, 256, 0, stream>>>(reprb, Wrb, br, rb, 128, 1024, 1024);
  gemm_bt<0><<<8, 256, 0, stream>>>(reprb, Whb, bh, hb, 128, 1024, 1024);

  // chunk probs
  chunk_probs_k<<<dim3(16, 2), 1024, 0, stream>>>(rb, hb, probs);

  // F^T = V^T K per chunk (MFMA)
  f_kernel<<<1024, 256, 0, stream>>>(Kb, Vb, fbuf);

  // retrieved^T (coalesced mini-GEMM)
  retrieve_k<<<dim3(32, 8), 256, 0, stream>>>(probs, fbuf, retT);

  // fused long-term + local attention
  attn_k<<<1024, 256, 0, stream>>>(Qb, Kb, Vb, retT, attnb);

  // output projection (fp32 out)
  gemm_bt<1><<<512, 256, 0, stream>>>(attnb, Wob, bo, d_out, 8192, 1024, 1024);
}

// Round 3
// 293.222 us; speedup vs baseline: 1.3612x; 1.1379x over previous
//
#include <hip/hip_runtime.h>
#include <stdint.h>

#define NEG9 (-1e9f)

typedef __attribute__((ext_vector_type(8))) short short8;
typedef __attribute__((ext_vector_type(8))) unsigned short ushort8;
typedef __attribute__((ext_vector_type(4))) unsigned short ushort4_t;
typedef __attribute__((ext_vector_type(4))) float f32x4;

#define MFMA_BF16(a,b,c) __builtin_amdgcn_mfma_f32_16x16x32_bf16((a),(b),(c),0,0,0)

__device__ __forceinline__ unsigned short f2bf(float f) {
  union { float f; unsigned int u; } x; x.f = f;
  unsigned int r = x.u + 0x7fffu + ((x.u >> 16) & 1u);
  return (unsigned short)(r >> 16);
}
__device__ __forceinline__ float bf2f(unsigned short h) {
  union { unsigned int u; float f; } x; x.u = ((unsigned int)h) << 16;
  return x.f;
}
__device__ __forceinline__ void gload_lds16(const unsigned short* g, unsigned short* l) {
  __builtin_amdgcn_global_load_lds(
      (const __attribute__((address_space(1))) unsigned int*)g,
      (__attribute__((address_space(3))) unsigned int*)l, 16, 0, 0);
}

// ---------------- fp32 -> bf16 convert ----------------
__global__ void cvt_f32_bf16(const float* __restrict__ in, unsigned short* __restrict__ out, int n4) {
  int i = blockIdx.x * blockDim.x + threadIdx.x;
  int stride = gridDim.x * blockDim.x;
  for (; i < n4; i += stride) {
    float4 v = ((const float4*)in)[i];
    ushort4_t o;
    o.x = f2bf(v.x); o.y = f2bf(v.y); o.z = f2bf(v.z); o.w = f2bf(v.w);
    ((ushort4_t*)out)[i] = o;
  }
}

// 6 weight matrices in one dispatch (blockIdx.y selects); dsts may be stacked
__global__ void cvt_w6(const float* a0, const float* a1, const float* a2,
                       const float* a3, const float* a4, const float* a5,
                       unsigned short* b0, unsigned short* b1, unsigned short* b2,
                       unsigned short* b3, unsigned short* b4, unsigned short* b5) {
  const float* in; unsigned short* out;
  switch (blockIdx.y) {
    case 0: in = a0; out = b0; break;
    case 1: in = a1; out = b1; break;
    case 2: in = a2; out = b2; break;
    case 3: in = a3; out = b3; break;
    case 4: in = a4; out = b4; break;
    default: in = a5; out = b5; break;
  }
  const int n4 = 262144;
  int i = blockIdx.x * blockDim.x + threadIdx.x;
  int stride = gridDim.x * blockDim.x;
  for (; i < n4; i += stride) {
    float4 v = ((const float4*)in)[i];
    ushort4_t o;
    o.x = f2bf(v.x); o.y = f2bf(v.y); o.z = f2bf(v.z); o.w = f2bf(v.w);
    ((ushort4_t*)out)[i] = o;
  }
}

// ---------------- m97-style GEMM: C[M,N] = A[M,K] * W[N,K]^T + bias ----------------
template<int OUT_F32>
__global__ __launch_bounds__(256)
void gemm_bt(const unsigned short* __restrict__ A,
             const unsigned short* __restrict__ W,
             const float* __restrict__ bias,
             void* __restrict__ Cout,
             int M, int N, int K) {
  __shared__ unsigned short As[128*32];
  __shared__ unsigned short Bs[128*32];
  const int t = threadIdx.x;
  const int lane = t & 63;
  const int wave = t >> 6;
  const int wr = wave >> 1, wc = wave & 1;
  const int lr = lane & 15;
  const int lk = (lane >> 4) << 3;

  const int nbn = N >> 7;
  const int nwg = (M >> 7) * nbn;
  int bid = blockIdx.x;
  if ((nwg & 7) == 0) { int q = nwg >> 3; bid = (bid & 7) * q + (bid >> 3); }
  const int bm = bid / nbn, bn = bid % nbn;

  const long rowA0 = (long)bm * 128;
  const long rowB0 = (long)bn * 128;
  const int srow = t >> 2;
  const int scol = (t & 3) << 3;

  f32x4 acc[4][4];
#pragma unroll
  for (int m = 0; m < 4; m++)
#pragma unroll
    for (int n = 0; n < 4; n++) acc[m][n] = f32x4{0.f,0.f,0.f,0.f};

  for (int k0 = 0; k0 < K; k0 += 32) {
    const unsigned short* ga = A + (rowA0 + srow) * K + k0 + scol;
    const unsigned short* gb = W + (rowB0 + srow) * K + k0 + scol;
    gload_lds16(ga,              As + t*8);
    gload_lds16(ga + (long)64*K, As + t*8 + 2048);
    gload_lds16(gb,              Bs + t*8);
    gload_lds16(gb + (long)64*K, Bs + t*8 + 2048);
    __syncthreads();
    short8 af[4], bf[4];
#pragma unroll
    for (int m = 0; m < 4; m++) af[m] = *(const short8*)&As[(wr*64 + m*16 + lr)*32 + lk];
#pragma unroll
    for (int n = 0; n < 4; n++) bf[n] = *(const short8*)&Bs[(wc*64 + n*16 + lr)*32 + lk];
#pragma unroll
    for (int m = 0; m < 4; m++)
#pragma unroll
      for (int n = 0; n < 4; n++)
        acc[m][n] = MFMA_BF16(af[m], bf[n], acc[m][n]);
    __syncthreads();
  }

  const int rg4 = (lane >> 4) * 4;
#pragma unroll
  for (int m = 0; m < 4; m++) {
#pragma unroll
    for (int n = 0; n < 4; n++) {
      long row = rowA0 + wr*64 + m*16 + rg4;
      long col = rowB0 + wc*64 + n*16 + lr;
      float bv = bias[col];
#pragma unroll
      for (int r = 0; r < 4; r++) {
        float v = acc[m][n][r] + bv;
        if (OUT_F32) ((float*)Cout)[(row + r) * N + col] = v;
        else ((unsigned short*)Cout)[(row + r) * N + col] = f2bf(v);
      }
    }
  }
}

// ---------------- fused QKV GEMM: N=3072 stacked weights, demux epilogue ----------------
__global__ __launch_bounds__(256)
void gemm_qkv(const unsigned short* __restrict__ A,
              const unsigned short* __restrict__ Wqkv,
              const float* __restrict__ bq, const float* __restrict__ bk,
              const float* __restrict__ bv,
              unsigned short* __restrict__ Q, unsigned short* __restrict__ Kb,
              unsigned short* __restrict__ V) {
  const int K = 1024;
  __shared__ unsigned short As[128*32];
  __shared__ unsigned short Bs[128*32];
  const int t = threadIdx.x;
  const int lane = t & 63;
  const int wave = t >> 6;
  const int wr = wave >> 1, wc = wave & 1;
  const int lr = lane & 15;
  const int lk = (lane >> 4) << 3;

  const int nbn = 24;            // 3072/128
  int bid = blockIdx.x;          // nwg = 64*24 = 1536, %8==0
  { int q = 1536 >> 3; bid = (bid & 7) * q + (bid >> 3); }
  const int bm = bid / nbn, bn = bid % nbn;

  const long rowA0 = (long)bm * 128;
  const long rowB0 = (long)bn * 128;
  const int srow = t >> 2;
  const int scol = (t & 3) << 3;

  f32x4 acc[4][4];
#pragma unroll
  for (int m = 0; m < 4; m++)
#pragma unroll
    for (int n = 0; n < 4; n++) acc[m][n] = f32x4{0.f,0.f,0.f,0.f};

  for (int k0 = 0; k0 < K; k0 += 32) {
    const unsigned short* ga = A + (rowA0 + srow) * K + k0 + scol;
    const unsigned short* gb = Wqkv + (rowB0 + srow) * K + k0 + scol;
    gload_lds16(ga,              As + t*8);
    gload_lds16(ga + (long)64*K, As + t*8 + 2048);
    gload_lds16(gb,              Bs + t*8);
    gload_lds16(gb + (long)64*K, Bs + t*8 + 2048);
    __syncthreads();
    short8 af[4], bf[4];
#pragma unroll
    for (int m = 0; m < 4; m++) af[m] = *(const short8*)&As[(wr*64 + m*16 + lr)*32 + lk];
#pragma unroll
    for (int n = 0; n < 4; n++) bf[n] = *(const short8*)&Bs[(wc*64 + n*16 + lr)*32 + lk];
#pragma unroll
    for (int m = 0; m < 4; m++)
#pragma unroll
      for (int n = 0; n < 4; n++)
        acc[m][n] = MFMA_BF16(af[m], bf[n], acc[m][n]);
    __syncthreads();
  }

  // demux: which buffer this column-block belongs to (uniform per block)
  const int which = bn >> 3;
  unsigned short* Co = (which == 0) ? Q : (which == 1) ? Kb : V;
  const float* bsel = (which == 0) ? bq : (which == 1) ? bk : bv;
  const long colbase = rowB0 - (long)which * 1024;

  const int rg4 = (lane >> 4) * 4;
#pragma unroll
  for (int m = 0; m < 4; m++) {
#pragma unroll
    for (int n = 0; n < 4; n++) {
      long row = rowA0 + wr*64 + m*16 + rg4;
      long col = colbase + wc*64 + n*16 + lr;
      float bvv = bsel[col];
#pragma unroll
      for (int r = 0; r < 4; r++)
        Co[(row + r) * 1024 + col] = f2bf(acc[m][n][r] + bvv);
    }
  }
}

// ---------------- chunk_repr gather + pad to 128 rows; also stack r/h bias ----------------
__global__ void repr_pad(const float* __restrict__ hs, unsigned short* __restrict__ out,
                         const float* __restrict__ br, const float* __restrict__ bh,
                         float* __restrict__ brh) {
  int r = blockIdx.x;   // 0..127
  int t = threadIdx.x;  // 256
  long base = (long)r * 1024;
  if (r < 64) {
    int b = r >> 5, c = r & 31;
    const float* src = hs + ((long)(b*4096 + c*128 + 127)) * 1024;
#pragma unroll
    for (int j = 0; j < 4; j++) { int idx = t + j*256; out[base + idx] = f2bf(src[idx]); }
  } else {
#pragma unroll
    for (int j = 0; j < 4; j++) out[base + t + j*256] = 0;
    if (r == 64) {
#pragma unroll
      for (int j = 0; j < 4; j++) { int idx = t + j*256; brh[idx] = br[idx]; }
    } else if (r == 65) {
#pragma unroll
      for (int j = 0; j < 4; j++) { int idx = t + j*256; brh[1024 + idx] = bh[idx]; }
    }
  }
}

// ---------------- chunk scores + softmax -> probs [B,H,32,32] fp32 ----------------
// rbh: [128][2048], cols 0-1023 = r-proj, 1024-2047 = h-proj
__global__ __launch_bounds__(1024) void chunk_probs_k(
    const unsigned short* __restrict__ rbh,
    float* __restrict__ probs) {
  __shared__ float rt[32][65];
  __shared__ float ht[32][65];
  int h = blockIdx.x, b = blockIdx.y;
  int t = threadIdx.x;
#pragma unroll
  for (int j = 0; j < 2; j++) {
    int idx = t + j*1024;
    int c = idx >> 6, d = idx & 63;
    rt[c][d] = bf2f(rbh[(long)(b*32 + c)*2048 + h*64 + d]);
    ht[c][d] = bf2f(rbh[(long)(b*32 + c)*2048 + 1024 + h*64 + d]);
  }
  __syncthreads();
  int e = t & 31, c = t >> 5;
  float s = 0.f;
#pragma unroll
  for (int d = 0; d < 64; d++) s += rt[c][d] * ht[e][d];
  s *= 0.125f;
  if (e < c) s = NEG9;
  float m = s;
#pragma unroll
  for (int off = 16; off > 0; off >>= 1) m = fmaxf(m, __shfl_xor(m, off, 32));
  float p = __expf(s - m);
  float sum = p;
#pragma unroll
  for (int off = 16; off > 0; off >>= 1) sum += __shfl_xor(sum, off, 32);
  probs[(((long)(b*16 + h))*32 + c)*32 + e] = p / sum;
}

// ---------------- F^T = V^T K per chunk via MFMA: fbuf[bid][e*64+d] ----------------
__global__ __launch_bounds__(256) void f_kernel(
    const unsigned short* __restrict__ Kb, const unsigned short* __restrict__ Vb,
    unsigned short* __restrict__ f) {
  __shared__ unsigned short vT[64*136];   // [e][s] padded
  __shared__ unsigned short kT[64*136];   // [d][s] padded
  int bid = blockIdx.x;
  int c = bid & 31, h = (bid >> 5) & 15, b = bid >> 9;
  int t = threadIdx.x;
  const unsigned short* kg = Kb + ((long)(b*4096 + c*128))*1024 + h*64;
  const unsigned short* vg = Vb + ((long)(b*4096 + c*128))*1024 + h*64;
  {
    int eq = t & 7, sq = t >> 3;          // eq: e-block of 8, sq: s-quad
    int s0 = sq*4, e0 = eq*8;
    ushort8 v[4], k[4];
#pragma unroll
    for (int r = 0; r < 4; r++) {
      v[r] = *(const ushort8*)&vg[(long)(s0 + r)*1024 + e0];
      k[r] = *(const ushort8*)&kg[(long)(s0 + r)*1024 + e0];
    }
#pragma unroll
    for (int x = 0; x < 8; x++) {
      ushort4_t pv, pk;
      pv.x = v[0][x]; pv.y = v[1][x]; pv.z = v[2][x]; pv.w = v[3][x];
      pk.x = k[0][x]; pk.y = k[1][x]; pk.z = k[2][x]; pk.w = k[3][x];
      *(ushort4_t*)&vT[(e0 + x)*136 + s0] = pv;
      *(ushort4_t*)&kT[(e0 + x)*136 + s0] = pk;
    }
  }
  __syncthreads();
  const int lane = t & 63, w = t >> 6;
  const int lr = lane & 15, lk = (lane >> 4) << 3;
  const int rg4 = (lane >> 4) * 4;
  const int e0w = (w & 1) * 32, d0w = (w >> 1) * 32;

  f32x4 acc[2][2];
#pragma unroll
  for (int m = 0; m < 2; m++)
#pragma unroll
    for (int n = 0; n < 2; n++) acc[m][n] = f32x4{0.f,0.f,0.f,0.f};
#pragma unroll
  for (int kk = 0; kk < 4; kk++) {
    short8 af[2], bf[2];
#pragma unroll
    for (int m = 0; m < 2; m++) af[m] = *(const short8*)&vT[(e0w + m*16 + lr)*136 + kk*32 + lk];
#pragma unroll
    for (int n = 0; n < 2; n++) bf[n] = *(const short8*)&kT[(d0w + n*16 + lr)*136 + kk*32 + lk];
#pragma unroll
    for (int m = 0; m < 2; m++)
#pragma unroll
      for (int n = 0; n < 2; n++) acc[m][n] = MFMA_BF16(af[m], bf[n], acc[m][n]);
  }
  unsigned short* fo = f + (long)bid * 4096;
#pragma unroll
  for (int m = 0; m < 2; m++)
#pragma unroll
    for (int n = 0; n < 2; n++)
#pragma unroll
      for (int r = 0; r < 4; r++)
        fo[(e0w + m*16 + rg4 + r)*64 + d0w + n*16 + lr] = f2bf(acc[m][n][r]);
}

// ---------------- retrieved^T: retT[bh,c][x] = sum_ec probs[bh,c,ec] fbuf[bh,ec][x] ----------------
__global__ __launch_bounds__(256) void retrieve_k(
    const float* __restrict__ probs, const unsigned short* __restrict__ f,
    unsigned short* __restrict__ retT) {
  __shared__ float PL[1024];
  int bh = blockIdx.x;   // 0..31
  int xt = blockIdx.y;   // 0..7
  int t = threadIdx.x;   // 256
  *(float4*)&PL[t*4] = *(const float4*)&probs[(long)bh*1024 + t*4];
  __syncthreads();
  const unsigned int* fb = (const unsigned int*)(f + (long)bh*32*4096);
  const int xo = xt*256 + t;
  unsigned int fv[32];
#pragma unroll
  for (int ec = 0; ec < 32; ec++) fv[ec] = fb[ec*2048 + xo];
  unsigned int* ro = (unsigned int*)retT + (long)bh*32*2048 + xo;
  for (int c = 0; c < 32; c++) {
    float a0 = 0.f, a1 = 0.f;
#pragma unroll
    for (int e4 = 0; e4 < 8; e4++) {
      float4 p = *(const float4*)&PL[c*32 + e4*4];
#pragma unroll
      for (int j = 0; j < 4; j++) {
        unsigned int v = fv[e4*4 + j];
        union { unsigned int u; float ff; } lo, hi;
        lo.u = v << 16; hi.u = v & 0xffff0000u;
        a0 += p[j] * lo.ff;
        a1 += p[j] * hi.ff;
      }
    }
    ro[(long)c*2048] = (unsigned int)f2bf(a0) | ((unsigned int)f2bf(a1) << 16);
  }
}

// ---------------- fused attention per (b,h,c) ----------------
// ks, rT XOR-swizzled (byte ^= (row&7)<<4) to kill the 128B-row-stride 16-way bank conflict.
__global__ __launch_bounds__(256) void attn_k(
    const unsigned short* __restrict__ Qb,
    const unsigned short* __restrict__ Kb,
    const unsigned short* __restrict__ Vb,
    const unsigned short* __restrict__ retT,
    unsigned short* __restrict__ attn) {
  __shared__ unsigned short ks[128*64];   // [t][d], swizzled
  __shared__ unsigned short vT[64*136];   // [e][t] padded
  __shared__ unsigned short rT[64*64];    // [e'][d], swizzled
  __shared__ unsigned short P[128*136];   // [s][t] padded
  const int bid = blockIdx.x;
  const int c = bid & 31, h = (bid >> 5) & 15, b = bid >> 9;
  const int t = threadIdx.x;
  const int lane = t & 63, w = t >> 6;
  const int lr = lane & 15, lk = (lane >> 4) << 3;
  const int rg4 = (lane >> 4) * 4;

  const long rowbase = (long)(b*4096 + c*128);
  const unsigned short* kg = Kb + rowbase*1024 + h*64;
  const unsigned short* vg = Vb + rowbase*1024 + h*64;
  const unsigned short* qg = Qb + rowbase*1024 + h*64;
  const unsigned short* rtg = retT + (long)bid*4096;

  {
    // ks: linear LDS dest, pre-swizzled global source (rule #21)
    const int off = (t & 7) << 4;         // byte col within 128B row
#pragma unroll
    for (int i = 0; i < 4; i++) {
      int row = (t >> 3) + i*32;
      int srcoff = off ^ ((row & 7) << 4);
      gload_lds16(kg + (long)row*1024 + (srcoff >> 1), ks + t*8 + i*2048);
    }
    // rT: same swizzle (64 rows x 128B)
#pragma unroll
    for (int i = 0; i < 2; i++) {
      int row = ((t + i*256) >> 3);
      int srcoff = off ^ ((row & 7) << 4);
      gload_lds16(rtg + (long)row*64 + (srcoff >> 1), rT + (t + i*256)*8);
    }
  }
  {
    // vT transpose staging: 4-row packed ds_write_b64
    int eq = t & 7, sq = t >> 3;
    int s0 = sq*4, e0 = eq*8;
    ushort8 v[4];
#pragma unroll
    for (int r = 0; r < 4; r++) v[r] = *(const ushort8*)&vg[(long)(s0 + r)*1024 + e0];
#pragma unroll
    for (int x = 0; x < 8; x++) {
      ushort4_t pv;
      pv.x = v[0][x]; pv.y = v[1][x]; pv.z = v[2][x]; pv.w = v[3][x];
      *(ushort4_t*)&vT[(e0 + x)*136 + s0] = pv;
    }
  }
  __syncthreads();

  // QK^T: rows w*32..w*32+31, all 128 cols
  short8 qa[2][2];
#pragma unroll
  for (int m = 0; m < 2; m++)
#pragma unroll
    for (int kk = 0; kk < 2; kk++)
      qa[m][kk] = *(const short8*)&qg[(long)(w*32 + m*16 + lr)*1024 + kk*32 + lk];
  f32x4 scf[2][8];
#pragma unroll
  for (int m = 0; m < 2; m++)
#pragma unroll
    for (int n = 0; n < 8; n++) scf[m][n] = f32x4{0.f,0.f,0.f,0.f};
#pragma unroll
  for (int n = 0; n < 8; n++) {
    const int krow = n*16 + lr;
    const int swzmask = (krow & 7) << 4;
#pragma unroll
    for (int kk = 0; kk < 2; kk++) {
      int colb = (kk*64 + ((lane >> 4) << 4)) ^ swzmask;
      short8 kf = *(const short8*)&ks[krow*64 + (colb >> 1)];
#pragma unroll
      for (int m = 0; m < 2; m++) scf[m][n] = MFMA_BF16(qa[m][kk], kf, scf[m][n]);
    }
  }

  // masked softmax per row; write P (bf16) to LDS
  float rsum[2][4];
#pragma unroll
  for (int m = 0; m < 2; m++) {
#pragma unroll
    for (int r = 0; r < 4; r++) {
      int srow = w*32 + m*16 + rg4 + r;
      float vals[8];
      float mx = -1e30f;
#pragma unroll
      for (int n = 0; n < 8; n++) {
        int tcol = n*16 + lr;
        float v_ = scf[m][n][r] * 0.125f;
        if (tcol < srow) v_ = NEG9;
        vals[n] = v_;
        mx = fmaxf(mx, v_);
      }
#pragma unroll
      for (int off = 1; off < 16; off <<= 1) mx = fmaxf(mx, __shfl_xor(mx, off, 16));
      float sum = 0.f;
#pragma unroll
      for (int n = 0; n < 8; n++) {
        float p = __expf(vals[n] - mx);
        sum += p;
        P[srow*136 + n*16 + lr] = f2bf(p);
      }
#pragma unroll
      for (int off = 1; off < 16; off <<= 1) sum += __shfl_xor(sum, off, 16);
      rsum[m][r] = sum;
    }
  }

  // long_term: qa @ rT (swizzled reads)
  f32x4 outa[2][4];
#pragma unroll
  for (int m = 0; m < 2; m++)
#pragma unroll
    for (int n = 0; n < 4; n++) outa[m][n] = f32x4{0.f,0.f,0.f,0.f};
#pragma unroll
  for (int n = 0; n < 4; n++) {
    const int rrow = n*16 + lr;
    const int swzmask = (rrow & 7) << 4;
#pragma unroll
    for (int kk = 0; kk < 2; kk++) {
      int colb = (kk*64 + ((lane >> 4) << 4)) ^ swzmask;
      short8 rf = *(const short8*)&rT[rrow*64 + (colb >> 1)];
#pragma unroll
      for (int m = 0; m < 2; m++) outa[m][n] = MFMA_BF16(qa[m][kk], rf, outa[m][n]);
    }
  }

  // PV: P rows w*32.. (written by this wave) @ vT
  f32x4 pv[2][4];
#pragma unroll
  for (int m = 0; m < 2; m++)
#pragma unroll
    for (int n = 0; n < 4; n++) pv[m][n] = f32x4{0.f,0.f,0.f,0.f};
#pragma unroll
  for (int kk = 0; kk < 4; kk++) {
    short8 pa[2];
#pragma unroll
    for (int m = 0; m < 2; m++) pa[m] = *(const short8*)&P[(w*32 + m*16 + lr)*136 + kk*32 + lk];
#pragma unroll
    for (int n = 0; n < 4; n++) {
      short8 vf = *(const short8*)&vT[(n*16 + lr)*136 + kk*32 + lk];
#pragma unroll
      for (int m = 0; m < 2; m++) pv[m][n] = MFMA_BF16(pa[m], vf, pv[m][n]);
    }
  }

  unsigned short* ao = attn + rowbase*1024 + h*64;
#pragma unroll
  for (int m = 0; m < 2; m++)
#pragma unroll
    for (int n = 0; n < 4; n++)
#pragma unroll
      for (int r = 0; r < 4; r++) {
        int srow = w*32 + m*16 + rg4 + r;
        float v_ = pv[m][n][r] / rsum[m][r] + outa[m][n][r];
        ao[(long)srow*1024 + n*16 + lr] = f2bf(v_);
      }
}

// ---------------- launch ----------------
extern "C" void kernel_launch(void* const* d_in, const int* in_sizes, int n_in,
                              void* d_out, int out_size, void* d_ws, size_t ws_size,
                              hipStream_t stream) {
  const float* hs = (const float*)d_in[0];
  const float* Wq = (const float*)d_in[1];
  const float* bq = (const float*)d_in[2];
  const float* Wk = (const float*)d_in[3];
  const float* bk = (const float*)d_in[4];
  const float* Wv = (const float*)d_in[5];
  const float* bv = (const float*)d_in[6];
  const float* Wo = (const float*)d_in[7];
  const float* bo = (const float*)d_in[8];
  const float* Wr = (const float*)d_in[9];
  const float* br = (const float*)d_in[10];
  const float* Wh = (const float*)d_in[11];
  const float* bh = (const float*)d_in[12];

  char* p = (char*)d_ws;
  unsigned short* hsb  = (unsigned short*)p; p += (size_t)8192*1024*2;
  unsigned short* Wqkv = (unsigned short*)p; p += (size_t)3072*1024*2;
  unsigned short* Wob  = (unsigned short*)p; p += (size_t)1024*1024*2;
  unsigned short* Wrh  = (unsigned short*)p; p += (size_t)2048*1024*2;
  unsigned short* Qb   = (unsigned short*)p; p += (size_t)8192*1024*2;
  unsigned short* Kb   = (unsigned short*)p; p += (size_t)8192*1024*2;
  unsigned short* Vb   = (unsigned short*)p; p += (size_t)8192*1024*2;
  unsigned short* reprb= (unsigned short*)p; p += (size_t)128*1024*2;
  unsigned short* rbhb = (unsigned short*)p; p += (size_t)128*2048*2;
  float*          brh  = (float*)p;          p += (size_t)2048*4;
  float*          probs= (float*)p;          p += (size_t)2*16*32*32*4;
  unsigned short* fbuf = (unsigned short*)p; p += (size_t)2*16*32*4096*2;
  unsigned short* retT = (unsigned short*)p; p += (size_t)2*16*32*4096*2;
  unsigned short* attnb = hsb;  // overlay: hsb dead after QKV+r/h GEMMs

  // converts
  cvt_f32_bf16<<<8192, 256, 0, stream>>>(hs, hsb, 2097152);
  cvt_w6<<<dim3(256, 6), 256, 0, stream>>>(Wq, Wk, Wv, Wo, Wr, Wh,
                                           Wqkv, Wqkv + (size_t)1024*1024,
                                           Wqkv + (size_t)2048*1024,
                                           Wob, Wrh, Wrh + (size_t)1024*1024);
  repr_pad<<<128, 256, 0, stream>>>(hs, reprb, br, bh, brh);

  // fused QKV projection
  gemm_qkv<<<1536, 256, 0, stream>>>(hsb, Wqkv, bq, bk, bv, Qb, Kb, Vb);

  // fused r/h projection (M padded to 128, N=2048)
  gemm_bt<0><<<16, 256, 0, stream>>>(reprb, Wrh, brh, rbhb, 128, 2048, 1024);

  // chunk probs
  chunk_probs_k<<<dim3(16, 2), 1024, 0, stream>>>(rbhb, probs);

  // F^T = V^T K per chunk (MFMA)
  f_kernel<<<1024, 256, 0, stream>>>(Kb, Vb, fbuf);

  // retrieved^T (coalesced mini-GEMM)
  retrieve_k<<<dim3(32, 8), 256, 0, stream>>>(probs, fbuf, retT);

  // fused long-term + local attention
  attn_k<<<1024, 256, 0, stream>>>(Qb, Kb, Vb, retT, attnb);

  // output projection (fp32 out)
  gemm_bt<1><<<512, 256, 0, stream>>>(attnb, Wob, bo, d_out, 8192, 1024, 1024);
}

// Round 8
// 289.839 us; speedup vs baseline: 1.3771x; 1.0117x over previous
//
#include <hip/hip_runtime.h>
#include <stdint.h>

#define NEG9 (-1e9f)

typedef __attribute__((ext_vector_type(8))) short short8;
typedef __attribute__((ext_vector_type(8))) unsigned short ushort8;
typedef __attribute__((ext_vector_type(4))) unsigned short ushort4_t;
typedef __attribute__((ext_vector_type(4))) float f32x4;

#define MFMA_BF16(a,b,c) __builtin_amdgcn_mfma_f32_16x16x32_bf16((a),(b),(c),0,0,0)

__device__ __forceinline__ unsigned short f2bf(float f) {
  union { float f; unsigned int u; } x; x.f = f;
  unsigned int r = x.u + 0x7fffu + ((x.u >> 16) & 1u);
  return (unsigned short)(r >> 16);
}
__device__ __forceinline__ float bf2f(unsigned short h) {
  union { unsigned int u; float f; } x; x.u = ((unsigned int)h) << 16;
  return x.f;
}
__device__ __forceinline__ void gload_lds16(const unsigned short* g, unsigned short* l) {
  __builtin_amdgcn_global_load_lds(
      (const __attribute__((address_space(1))) unsigned int*)g,
      (__attribute__((address_space(3))) unsigned int*)l, 16, 0, 0);
}

// ---------------- fp32 -> bf16 convert ----------------
__global__ void cvt_f32_bf16(const float* __restrict__ in, unsigned short* __restrict__ out, int n4) {
  int i = blockIdx.x * blockDim.x + threadIdx.x;
  int stride = gridDim.x * blockDim.x;
  for (; i < n4; i += stride) {
    float4 v = ((const float4*)in)[i];
    ushort4_t o;
    o.x = f2bf(v.x); o.y = f2bf(v.y); o.z = f2bf(v.z); o.w = f2bf(v.w);
    ((ushort4_t*)out)[i] = o;
  }
}

__global__ void cvt_w6(const float* a0, const float* a1, const float* a2,
                       const float* a3, const float* a4, const float* a5,
                       unsigned short* b0, unsigned short* b1, unsigned short* b2,
                       unsigned short* b3, unsigned short* b4, unsigned short* b5) {
  const float* in; unsigned short* out;
  switch (blockIdx.y) {
    case 0: in = a0; out = b0; break;
    case 1: in = a1; out = b1; break;
    case 2: in = a2; out = b2; break;
    case 3: in = a3; out = b3; break;
    case 4: in = a4; out = b4; break;
    default: in = a5; out = b5; break;
  }
  const int n4 = 262144;
  int i = blockIdx.x * blockDim.x + threadIdx.x;
  int stride = gridDim.x * blockDim.x;
  for (; i < n4; i += stride) {
    float4 v = ((const float4*)in)[i];
    ushort4_t o;
    o.x = f2bf(v.x); o.y = f2bf(v.y); o.z = f2bf(v.z); o.w = f2bf(v.w);
    ((ushort4_t*)out)[i] = o;
  }
}

// =======================================================================
// 8-phase 256x256 GEMM, BK=64, 512 threads (8 waves 2Mx4N), dbuf LDS 128KiB
// C[M,N] = A[M,K] @ W[N,K]^T + bias.
// MODE 0: bf16 out (o0,b0). MODE 1: fp32 out (o0,b0). MODE 2: QKV demux.
// Requires M%256==0, N%256==0, K%64==0, nwg%8==0.
// =======================================================================
// stage one 128x64 half-tile: linear LDS dest, source pre-swizzled byte^=(row&7)<<4
__device__ __forceinline__ void stage_half(const unsigned short* __restrict__ g, int ldg,
                                           unsigned short* lh, int t) {
#pragma unroll
  for (int j = 0; j < 2; j++) {
    int idx = j*512 + t;
    int rowh = idx >> 3;
    int colb = (idx & 7) << 4;
    int scol = colb ^ ((rowh & 7) << 4);
    gload_lds16(g + (long)rowh*ldg + (scol >> 1), lh + idx*8);
  }
}

template<int MODE>
__global__ __launch_bounds__(512, 2)
void gemm8(const unsigned short* __restrict__ A,
           const unsigned short* __restrict__ W,
           const float* __restrict__ b0, const float* __restrict__ b1,
           const float* __restrict__ b2,
           void* __restrict__ o0, void* __restrict__ o1, void* __restrict__ o2,
           int M, int N, int K) {
  __shared__ unsigned short lds[2][2][16384];  // [buf][0=A,1=B][256*64]
  const int t = threadIdx.x;
  const int lane = t & 63;
  const int w = t >> 6;
  const int wm = w >> 2, wn = w & 3;
  const int lr = lane & 15, lp = lane >> 4;

  const int nbn = N >> 8;
  const int nwg = (M >> 8) * nbn;
  int bid = blockIdx.x;
  { int q = nwg >> 3; bid = (bid & 7) * q + (bid >> 3); }
  const int bm = bid / nbn, bn = bid % nbn;
  const long rowA0 = (long)bm << 8;
  const long rowB0 = (long)bn << 8;
  const int KT = K >> 6;

  // prologue: issue order B(0)h0,h1, A(0)h0,h1, B(1)h0,h1  (12 loads)
  stage_half(W + rowB0*K,         K, &lds[0][1][0],    t);
  stage_half(W + (rowB0+128)*K,   K, &lds[0][1][8192], t);
  stage_half(A + rowA0*K,         K, &lds[0][0][0],    t);
  stage_half(A + (rowA0+128)*K,   K, &lds[0][0][8192], t);
  if (KT > 1) {
    stage_half(W + rowB0*K + 64,       K, &lds[1][1][0],    t);
    stage_half(W + (rowB0+128)*K + 64, K, &lds[1][1][8192], t);
  }
  asm volatile("s_waitcnt vmcnt(4)" ::: "memory");
  __builtin_amdgcn_s_barrier();

  f32x4 acc[8][4];
#pragma unroll
  for (int m = 0; m < 8; m++)
#pragma unroll
    for (int n = 0; n < 4; n++) acc[m][n] = f32x4{0.f,0.f,0.f,0.f};

  short8 af[4][2], bf0[2][2], bf1[2][2];

  for (int kt = 0; kt < KT; ++kt) {
    const int cur = kt & 1;
    const char* As = (const char*)&lds[cur][0][0];
    const char* Bs = (const char*)&lds[cur][1][0];

    // ---- phase 0: read A-qm0(8) + B-qn0(4); stage A(kt+1)h0; mfma (qm0,qn0)
#pragma unroll
    for (int mr = 0; mr < 4; mr++) {
      int row = wm*128 + mr*16 + lr;
      int sw = (row & 7) << 4;
#pragma unroll
      for (int kk = 0; kk < 2; kk++)
        af[mr][kk] = *(const short8*)(As + row*128 + ((kk*64 + lp*16) ^ sw));
    }
#pragma unroll
    for (int nr = 0; nr < 2; nr++) {
      int row = wn*64 + nr*16 + lr;
      int sw = (row & 7) << 4;
#pragma unroll
      for (int kk = 0; kk < 2; kk++)
        bf0[nr][kk] = *(const short8*)(Bs + row*128 + ((kk*64 + lp*16) ^ sw));
    }
    if (kt+1 < KT) stage_half(A + rowA0*K + (kt+1)*64, K, &lds[cur^1][0][0], t);
    __builtin_amdgcn_s_barrier();
    __builtin_amdgcn_s_setprio(1);
#pragma unroll
    for (int mr = 0; mr < 4; mr++)
#pragma unroll
      for (int nr = 0; nr < 2; nr++)
#pragma unroll
        for (int kk = 0; kk < 2; kk++)
          acc[mr][nr] = MFMA_BF16(af[mr][kk], bf0[nr][kk], acc[mr][nr]);
    __builtin_amdgcn_s_setprio(0);
    __builtin_amdgcn_s_barrier();

    // ---- phase 1: read B-qn1(4); stage A(kt+1)h1; mfma (qm0,qn1)
#pragma unroll
    for (int nr = 0; nr < 2; nr++) {
      int row = wn*64 + 32 + nr*16 + lr;
      int sw = (row & 7) << 4;
#pragma unroll
      for (int kk = 0; kk < 2; kk++)
        bf1[nr][kk] = *(const short8*)(Bs + row*128 + ((kk*64 + lp*16) ^ sw));
    }
    if (kt+1 < KT) stage_half(A + (rowA0+128)*K + (kt+1)*64, K, &lds[cur^1][0][8192], t);
    __builtin_amdgcn_s_barrier();
    __builtin_amdgcn_s_setprio(1);
#pragma unroll
    for (int mr = 0; mr < 4; mr++)
#pragma unroll
      for (int nr = 0; nr < 2; nr++)
#pragma unroll
        for (int kk = 0; kk < 2; kk++)
          acc[mr][2+nr] = MFMA_BF16(af[mr][kk], bf1[nr][kk], acc[mr][2+nr]);
    __builtin_amdgcn_s_setprio(0);
    __builtin_amdgcn_s_barrier();

    // ---- phase 2: read A-qm1(8); stage B(kt+2)h0 (own-buf B free after ph1); mfma (qm1,qn1)
#pragma unroll
    for (int mr = 0; mr < 4; mr++) {
      int row = wm*128 + 64 + mr*16 + lr;
      int sw = (row & 7) << 4;
#pragma unroll
      for (int kk = 0; kk < 2; kk++)
        af[mr][kk] = *(const short8*)(As + row*128 + ((kk*64 + lp*16) ^ sw));
    }
    if (kt+2 < KT) stage_half(W + rowB0*K + (kt+2)*64, K, &lds[cur][1][0], t);
    __builtin_amdgcn_s_barrier();
    __builtin_amdgcn_s_setprio(1);
#pragma unroll
    for (int mr = 0; mr < 4; mr++)
#pragma unroll
      for (int nr = 0; nr < 2; nr++)
#pragma unroll
        for (int kk = 0; kk < 2; kk++)
          acc[4+mr][2+nr] = MFMA_BF16(af[mr][kk], bf1[nr][kk], acc[4+mr][2+nr]);
    __builtin_amdgcn_s_setprio(0);
    __builtin_amdgcn_s_barrier();

    // ---- phase 3: stage B(kt+2)h1; mfma (qm1,qn0); counted vmcnt; barrier
    if (kt+2 < KT) stage_half(W + (rowB0+128)*K + (kt+2)*64, K, &lds[cur][1][8192], t);
    __builtin_amdgcn_s_barrier();
    __builtin_amdgcn_s_setprio(1);
#pragma unroll
    for (int mr = 0; mr < 4; mr++)
#pragma unroll
      for (int nr = 0; nr < 2; nr++)
#pragma unroll
        for (int kk = 0; kk < 2; kk++)
          acc[4+mr][nr] = MFMA_BF16(af[mr][kk], bf0[nr][kk], acc[4+mr][nr]);
    __builtin_amdgcn_s_setprio(0);
    if (kt+1 < KT) {
      if (kt+2 < KT) { asm volatile("s_waitcnt vmcnt(4)" ::: "memory"); }
      else           { asm volatile("s_waitcnt vmcnt(0)" ::: "memory"); }
    }
    __builtin_amdgcn_s_barrier();
  }

  // ---- epilogue
  if (MODE == 2) {
    const int which = (int)(rowB0 >> 10);
    unsigned short* Co = which==0 ? (unsigned short*)o0 : which==1 ? (unsigned short*)o1 : (unsigned short*)o2;
    const float* bb = which==0 ? b0 : which==1 ? b1 : b2;
    const long colbase = rowB0 - (long)which*1024;
#pragma unroll
    for (int m = 0; m < 8; m++)
#pragma unroll
      for (int n = 0; n < 4; n++) {
        long row = rowA0 + wm*128 + m*16 + lp*4;
        long col = colbase + wn*64 + n*16 + lr;
        float bv = bb[col];
#pragma unroll
        for (int r = 0; r < 4; r++)
          Co[(row + r)*1024 + col] = f2bf(acc[m][n][r] + bv);
      }
  } else {
#pragma unroll
    for (int m = 0; m < 8; m++)
#pragma unroll
      for (int n = 0; n < 4; n++) {
        long row = rowA0 + wm*128 + m*16 + lp*4;
        long col = rowB0 + wn*64 + n*16 + lr;
        float bv = b0[col];
#pragma unroll
        for (int r = 0; r < 4; r++) {
          float v = acc[m][n][r] + bv;
          if (MODE == 1) ((float*)o0)[(row + r)*N + col] = v;
          else ((unsigned short*)o0)[(row + r)*N + col] = f2bf(v);
        }
      }
  }
}

// ---------------- m97-style 128^2 GEMM (kept for the small r/h projection) ----------------
template<int OUT_F32>
__global__ __launch_bounds__(256)
void gemm_bt(const unsigned short* __restrict__ A,
             const unsigned short* __restrict__ W,
             const float* __restrict__ bias,
             void* __restrict__ Cout,
             int M, int N, int K) {
  __shared__ unsigned short As[128*32];
  __shared__ unsigned short Bs[128*32];
  const int t = threadIdx.x;
  const int lane = t & 63;
  const int wave = t >> 6;
  const int wr = wave >> 1, wc = wave & 1;
  const int lr = lane & 15;
  const int lk = (lane >> 4) << 3;

  const int nbn = N >> 7;
  const int nwg = (M >> 7) * nbn;
  int bid = blockIdx.x;
  if ((nwg & 7) == 0) { int q = nwg >> 3; bid = (bid & 7) * q + (bid >> 3); }
  const int bm = bid / nbn, bn = bid % nbn;

  const long rowA0 = (long)bm * 128;
  const long rowB0 = (long)bn * 128;
  const int srow = t >> 2;
  const int scol = (t & 3) << 3;

  f32x4 acc[4][4];
#pragma unroll
  for (int m = 0; m < 4; m++)
#pragma unroll
    for (int n = 0; n < 4; n++) acc[m][n] = f32x4{0.f,0.f,0.f,0.f};

  for (int k0 = 0; k0 < K; k0 += 32) {
    const unsigned short* ga = A + (rowA0 + srow) * K + k0 + scol;
    const unsigned short* gb = W + (rowB0 + srow) * K + k0 + scol;
    gload_lds16(ga,              As + t*8);
    gload_lds16(ga + (long)64*K, As + t*8 + 2048);
    gload_lds16(gb,              Bs + t*8);
    gload_lds16(gb + (long)64*K, Bs + t*8 + 2048);
    __syncthreads();
    short8 af[4], bf[4];
#pragma unroll
    for (int m = 0; m < 4; m++) af[m] = *(const short8*)&As[(wr*64 + m*16 + lr)*32 + lk];
#pragma unroll
    for (int n = 0; n < 4; n++) bf[n] = *(const short8*)&Bs[(wc*64 + n*16 + lr)*32 + lk];
#pragma unroll
    for (int m = 0; m < 4; m++)
#pragma unroll
      for (int n = 0; n < 4; n++)
        acc[m][n] = MFMA_BF16(af[m], bf[n], acc[m][n]);
    __syncthreads();
  }

  const int rg4 = (lane >> 4) * 4;
#pragma unroll
  for (int m = 0; m < 4; m++) {
#pragma unroll
    for (int n = 0; n < 4; n++) {
      long row = rowA0 + wr*64 + m*16 + rg4;
      long col = rowB0 + wc*64 + n*16 + lr;
      float bv = bias[col];
#pragma unroll
      for (int r = 0; r < 4; r++) {
        float v = acc[m][n][r] + bv;
        if (OUT_F32) ((float*)Cout)[(row + r) * N + col] = v;
        else ((unsigned short*)Cout)[(row + r) * N + col] = f2bf(v);
      }
    }
  }
}

// ---------------- chunk_repr gather + pad to 128 rows; also stack r/h bias ----------------
__global__ void repr_pad(const float* __restrict__ hs, unsigned short* __restrict__ out,
                         const float* __restrict__ br, const float* __restrict__ bh,
                         float* __restrict__ brh) {
  int r = blockIdx.x;
  int t = threadIdx.x;
  long base = (long)r * 1024;
  if (r < 64) {
    int b = r >> 5, c = r & 31;
    const float* src = hs + ((long)(b*4096 + c*128 + 127)) * 1024;
#pragma unroll
    for (int j = 0; j < 4; j++) { int idx = t + j*256; out[base + idx] = f2bf(src[idx]); }
  } else {
#pragma unroll
    for (int j = 0; j < 4; j++) out[base + t + j*256] = 0;
    if (r == 64) {
#pragma unroll
      for (int j = 0; j < 4; j++) { int idx = t + j*256; brh[idx] = br[idx]; }
    } else if (r == 65) {
#pragma unroll
      for (int j = 0; j < 4; j++) { int idx = t + j*256; brh[1024 + idx] = bh[idx]; }
    }
  }
}

// ---------------- chunk scores + softmax -> probs [B,H,32,32] fp32 ----------------
__global__ __launch_bounds__(1024) void chunk_probs_k(
    const unsigned short* __restrict__ rbh,
    float* __restrict__ probs) {
  __shared__ float rt[32][65];
  __shared__ float ht[32][65];
  int h = blockIdx.x, b = blockIdx.y;
  int t = threadIdx.x;
#pragma unroll
  for (int j = 0; j < 2; j++) {
    int idx = t + j*1024;
    int c = idx >> 6, d = idx & 63;
    rt[c][d] = bf2f(rbh[(long)(b*32 + c)*2048 + h*64 + d]);
    ht[c][d] = bf2f(rbh[(long)(b*32 + c)*2048 + 1024 + h*64 + d]);
  }
  __syncthreads();
  int e = t & 31, c = t >> 5;
  float s = 0.f;
#pragma unroll
  for (int d = 0; d < 64; d++) s += rt[c][d] * ht[e][d];
  s *= 0.125f;
  if (e < c) s = NEG9;
  float m = s;
#pragma unroll
  for (int off = 16; off > 0; off >>= 1) m = fmaxf(m, __shfl_xor(m, off, 32));
  float p = __expf(s - m);
  float sum = p;
#pragma unroll
  for (int off = 16; off > 0; off >>= 1) sum += __shfl_xor(sum, off, 32);
  probs[(((long)(b*16 + h))*32 + c)*32 + e] = p / sum;
}

// ---------------- F^T = V^T K per chunk via MFMA: fbuf[bid][e*64+d] ----------------
__global__ __launch_bounds__(256) void f_kernel(
    const unsigned short* __restrict__ Kb, const unsigned short* __restrict__ Vb,
    unsigned short* __restrict__ f) {
  __shared__ unsigned short vT[64*136];
  __shared__ unsigned short kT[64*136];
  int bid = blockIdx.x;
  int c = bid & 31, h = (bid >> 5) & 15, b = bid >> 9;
  int t = threadIdx.x;
  const unsigned short* kg = Kb + ((long)(b*4096 + c*128))*1024 + h*64;
  const unsigned short* vg = Vb + ((long)(b*4096 + c*128))*1024 + h*64;
  {
    int eq = t & 7, sq = t >> 3;
    int s0 = sq*4, e0 = eq*8;
    ushort8 v[4], k[4];
#pragma unroll
    for (int r = 0; r < 4; r++) {
      v[r] = *(const ushort8*)&vg[(long)(s0 + r)*1024 + e0];
      k[r] = *(const ushort8*)&kg[(long)(s0 + r)*1024 + e0];
    }
#pragma unroll
    for (int x = 0; x < 8; x++) {
      ushort4_t pv, pk;
      pv.x = v[0][x]; pv.y = v[1][x]; pv.z = v[2][x]; pv.w = v[3][x];
      pk.x = k[0][x]; pk.y = k[1][x]; pk.z = k[2][x]; pk.w = k[3][x];
      *(ushort4_t*)&vT[(e0 + x)*136 + s0] = pv;
      *(ushort4_t*)&kT[(e0 + x)*136 + s0] = pk;
    }
  }
  __syncthreads();
  const int lane = t & 63, w = t >> 6;
  const int lr = lane & 15, lk = (lane >> 4) << 3;
  const int rg4 = (lane >> 4) * 4;
  const int e0w = (w & 1) * 32, d0w = (w >> 1) * 32;

  f32x4 acc[2][2];
#pragma unroll
  for (int m = 0; m < 2; m++)
#pragma unroll
    for (int n = 0; n < 2; n++) acc[m][n] = f32x4{0.f,0.f,0.f,0.f};
#pragma unroll
  for (int kk = 0; kk < 4; kk++) {
    short8 af[2], bf[2];
#pragma unroll
    for (int m = 0; m < 2; m++) af[m] = *(const short8*)&vT[(e0w + m*16 + lr)*136 + kk*32 + lk];
#pragma unroll
    for (int n = 0; n < 2; n++) bf[n] = *(const short8*)&kT[(d0w + n*16 + lr)*136 + kk*32 + lk];
#pragma unroll
    for (int m = 0; m < 2; m++)
#pragma unroll
      for (int n = 0; n < 2; n++) acc[m][n] = MFMA_BF16(af[m], bf[n], acc[m][n]);
  }
  unsigned short* fo = f + (long)bid * 4096;
#pragma unroll
  for (int m = 0; m < 2; m++)
#pragma unroll
    for (int n = 0; n < 2; n++)
#pragma unroll
      for (int r = 0; r < 4; r++)
        fo[(e0w + m*16 + rg4 + r)*64 + d0w + n*16 + lr] = f2bf(acc[m][n][r]);
}

// ---------------- retrieved^T ----------------
__global__ __launch_bounds__(256) void retrieve_k(
    const float* __restrict__ probs, const unsigned short* __restrict__ f,
    unsigned short* __restrict__ retT) {
  __shared__ float PL[1024];
  int bh = blockIdx.x;
  int xt = blockIdx.y;
  int t = threadIdx.x;
  *(float4*)&PL[t*4] = *(const float4*)&probs[(long)bh*1024 + t*4];
  __syncthreads();
  const unsigned int* fb = (const unsigned int*)(f + (long)bh*32*4096);
  const int xo = xt*256 + t;
  unsigned int fv[32];
#pragma unroll
  for (int ec = 0; ec < 32; ec++) fv[ec] = fb[ec*2048 + xo];
  unsigned int* ro = (unsigned int*)retT + (long)bh*32*2048 + xo;
  for (int c = 0; c < 32; c++) {
    float a0 = 0.f, a1 = 0.f;
#pragma unroll
    for (int e4 = 0; e4 < 8; e4++) {
      float4 p = *(const float4*)&PL[c*32 + e4*4];
#pragma unroll
      for (int j = 0; j < 4; j++) {
        unsigned int v = fv[e4*4 + j];
        union { unsigned int u; float ff; } lo, hi;
        lo.u = v << 16; hi.u = v & 0xffff0000u;
        a0 += p[j] * lo.ff;
        a1 += p[j] * hi.ff;
      }
    }
    ro[(long)c*2048] = (unsigned int)f2bf(a0) | ((unsigned int)f2bf(a1) << 16);
  }
}

// ---------------- fused attention per (b,h,c) ----------------
__global__ __launch_bounds__(256) void attn_k(
    const unsigned short* __restrict__ Qb,
    const unsigned short* __restrict__ Kb,
    const unsigned short* __restrict__ Vb,
    const unsigned short* __restrict__ retT,
    unsigned short* __restrict__ attn) {
  __shared__ unsigned short ks[128*64];
  __shared__ unsigned short vT[64*136];
  __shared__ unsigned short rT[64*64];
  __shared__ unsigned short P[128*136];
  const int bid = blockIdx.x;
  const int c = bid & 31, h = (bid >> 5) & 15, b = bid >> 9;
  const int t = threadIdx.x;
  const int lane = t & 63, w = t >> 6;
  const int lr = lane & 15, lk = (lane >> 4) << 3;
  const int rg4 = (lane >> 4) * 4;

  const long rowbase = (long)(b*4096 + c*128);
  const unsigned short* kg = Kb + rowbase*1024 + h*64;
  const unsigned short* vg = Vb + rowbase*1024 + h*64;
  const unsigned short* qg = Qb + rowbase*1024 + h*64;
  const unsigned short* rtg = retT + (long)bid*4096;

  {
    const int off = (t & 7) << 4;
#pragma unroll
    for (int i = 0; i < 4; i++) {
      int row = (t >> 3) + i*32;
      int srcoff = off ^ ((row & 7) << 4);
      gload_lds16(kg + (long)row*1024 + (srcoff >> 1), ks + t*8 + i*2048);
    }
#pragma unroll
    for (int i = 0; i < 2; i++) {
      int row = ((t + i*256) >> 3);
      int srcoff = off ^ ((row & 7) << 4);
      gload_lds16(rtg + (long)row*64 + (srcoff >> 1), rT + (t + i*256)*8);
    }
  }
  {
    int eq = t & 7, sq = t >> 3;
    int s0 = sq*4, e0 = eq*8;
    ushort8 v[4];
#pragma unroll
    for (int r = 0; r < 4; r++) v[r] = *(const ushort8*)&vg[(long)(s0 + r)*1024 + e0];
#pragma unroll
    for (int x = 0; x < 8; x++) {
      ushort4_t pv;
      pv.x = v[0][x]; pv.y = v[1][x]; pv.z = v[2][x]; pv.w = v[3][x];
      *(ushort4_t*)&vT[(e0 + x)*136 + s0] = pv;
    }
  }
  __syncthreads();

  short8 qa[2][2];
#pragma unroll
  for (int m = 0; m < 2; m++)
#pragma unroll
    for (int kk = 0; kk < 2; kk++)
      qa[m][kk] = *(const short8*)&qg[(long)(w*32 + m*16 + lr)*1024 + kk*32 + lk];
  f32x4 scf[2][8];
#pragma unroll
  for (int m = 0; m < 2; m++)
#pragma unroll
    for (int n = 0; n < 8; n++) scf[m][n] = f32x4{0.f,0.f,0.f,0.f};
#pragma unroll
  for (int n = 0; n < 8; n++) {
    const int krow = n*16 + lr;
    const int swzmask = (krow & 7) << 4;
#pragma unroll
    for (int kk = 0; kk < 2; kk++) {
      int colb = (kk*64 + ((lane >> 4) << 4)) ^ swzmask;
      short8 kf = *(const short8*)&ks[krow*64 + (colb >> 1)];
#pragma unroll
      for (int m = 0; m < 2; m++) scf[m][n] = MFMA_BF16(qa[m][kk], kf, scf[m][n]);
    }
  }

  float rsum[2][4];
#pragma unroll
  for (int m = 0; m < 2; m++) {
#pragma unroll
    for (int r = 0; r < 4; r++) {
      int srow = w*32 + m*16 + rg4 + r;
      float vals[8];
      float mx = -1e30f;
#pragma unroll
      for (int n = 0; n < 8; n++) {
        int tcol = n*16 + lr;
        float v_ = scf[m][n][r] * 0.125f;
        if (tcol < srow) v_ = NEG9;
        vals[n] = v_;
        mx = fmaxf(mx, v_);
      }
#pragma unroll
      for (int off = 1; off < 16; off <<= 1) mx = fmaxf(mx, __shfl_xor(mx, off, 16));
      float sum = 0.f;
#pragma unroll
      for (int n = 0; n < 8; n++) {
        float p = __expf(vals[n] - mx);
        sum += p;
        P[srow*136 + n*16 + lr] = f2bf(p);
      }
#pragma unroll
      for (int off = 1; off < 16; off <<= 1) sum += __shfl_xor(sum, off, 16);
      rsum[m][r] = sum;
    }
  }

  f32x4 outa[2][4];
#pragma unroll
  for (int m = 0; m < 2; m++)
#pragma unroll
    for (int n = 0; n < 4; n++) outa[m][n] = f32x4{0.f,0.f,0.f,0.f};
#pragma unroll
  for (int n = 0; n < 4; n++) {
    const int rrow = n*16 + lr;
    const int swzmask = (rrow & 7) << 4;
#pragma unroll
    for (int kk = 0; kk < 2; kk++) {
      int colb = (kk*64 + ((lane >> 4) << 4)) ^ swzmask;
      short8 rf = *(const short8*)&rT[rrow*64 + (colb >> 1)];
#pragma unroll
      for (int m = 0; m < 2; m++) outa[m][n] = MFMA_BF16(qa[m][kk], rf, outa[m][n]);
    }
  }

  f32x4 pv[2][4];
#pragma unroll
  for (int m = 0; m < 2; m++)
#pragma unroll
    for (int n = 0; n < 4; n++) pv[m][n] = f32x4{0.f,0.f,0.f,0.f};
#pragma unroll
  for (int kk = 0; kk < 4; kk++) {
    short8 pa[2];
#pragma unroll
    for (int m = 0; m < 2; m++) pa[m] = *(const short8*)&P[(w*32 + m*16 + lr)*136 + kk*32 + lk];
#pragma unroll
    for (int n = 0; n < 4; n++) {
      short8 vf = *(const short8*)&vT[(n*16 + lr)*136 + kk*32 + lk];
#pragma unroll
      for (int m = 0; m < 2; m++) pv[m][n] = MFMA_BF16(pa[m], vf, pv[m][n]);
    }
  }

  unsigned short* ao = attn + rowbase*1024 + h*64;
#pragma unroll
  for (int m = 0; m < 2; m++)
#pragma unroll
    for (int n = 0; n < 4; n++)
#pragma unroll
      for (int r = 0; r < 4; r++) {
        int srow = w*32 + m*16 + rg4 + r;
        float v_ = pv[m][n][r] / rsum[m][r] + outa[m][n][r];
        ao[(long)srow*1024 + n*16 + lr] = f2bf(v_);
      }
}

// ---------------- launch ----------------
extern "C" void kernel_launch(void* const* d_in, const int* in_sizes, int n_in,
                              void* d_out, int out_size, void* d_ws, size_t ws_size,
                              hipStream_t stream) {
  const float* hs = (const float*)d_in[0];
  const float* Wq = (const float*)d_in[1];
  const float* bq = (const float*)d_in[2];
  const float* Wk = (const float*)d_in[3];
  const float* bk = (const float*)d_in[4];
  const float* Wv = (const float*)d_in[5];
  const float* bv = (const float*)d_in[6];
  const float* Wo = (const float*)d_in[7];
  const float* bo = (const float*)d_in[8];
  const float* Wr = (const float*)d_in[9];
  const float* br = (const float*)d_in[10];
  const float* Wh = (const float*)d_in[11];
  const float* bh = (const float*)d_in[12];

  char* p = (char*)d_ws;
  unsigned short* hsb  = (unsigned short*)p; p += (size_t)8192*1024*2;
  unsigned short* Wqkv = (unsigned short*)p; p += (size_t)3072*1024*2;
  unsigned short* Wob  = (unsigned short*)p; p += (size_t)1024*1024*2;
  unsigned short* Wrh  = (unsigned short*)p; p += (size_t)2048*1024*2;
  unsigned short* Qb   = (unsigned short*)p; p += (size_t)8192*1024*2;
  unsigned short* Kb   = (unsigned short*)p; p += (size_t)8192*1024*2;
  unsigned short* Vb   = (unsigned short*)p; p += (size_t)8192*1024*2;
  unsigned short* reprb= (unsigned short*)p; p += (size_t)128*1024*2;
  unsigned short* rbhb = (unsigned short*)p; p += (size_t)128*2048*2;
  float*          brh  = (float*)p;          p += (size_t)2048*4;
  float*          probs= (float*)p;          p += (size_t)2*16*32*32*4;
  unsigned short* fbuf = (unsigned short*)p; p += (size_t)2*16*32*4096*2;
  unsigned short* retT = (unsigned short*)p; p += (size_t)2*16*32*4096*2;
  unsigned short* attnb = hsb;  // overlay: hsb dead after QKV+r/h GEMMs

  cvt_f32_bf16<<<8192, 256, 0, stream>>>(hs, hsb, 2097152);
  cvt_w6<<<dim3(256, 6), 256, 0, stream>>>(Wq, Wk, Wv, Wo, Wr, Wh,
                                           Wqkv, Wqkv + (size_t)1024*1024,
                                           Wqkv + (size_t)2048*1024,
                                           Wob, Wrh, Wrh + (size_t)1024*1024);
  repr_pad<<<128, 256, 0, stream>>>(hs, reprb, br, bh, brh);

  // fused QKV projection (8-phase 256^2)
  gemm8<2><<<384, 512, 0, stream>>>(hsb, Wqkv, bq, bk, bv, Qb, Kb, Vb, 8192, 3072, 1024);

  // fused r/h projection (small M -> 128^2 kernel)
  gemm_bt<0><<<16, 256, 0, stream>>>(reprb, Wrh, brh, rbhb, 128, 2048, 1024);

  chunk_probs_k<<<dim3(16, 2), 1024, 0, stream>>>(rbhb, probs);
  f_kernel<<<1024, 256, 0, stream>>>(Kb, Vb, fbuf);
  retrieve_k<<<dim3(32, 8), 256, 0, stream>>>(probs, fbuf, retT);
  attn_k<<<1024, 256, 0, stream>>>(Qb, Kb, Vb, retT, attnb);

  // output projection (8-phase 256^2, fp32 out)
  gemm8<1><<<128, 512, 0, stream>>>(attnb, Wob, bo, nullptr, nullptr,
                                    d_out, nullptr, nullptr, 8192, 1024, 1024);
}

// Round 9
// 276.073 us; speedup vs baseline: 1.4458x; 1.0499x over previous
//
#include <hip/hip_runtime.h>
#include <stdint.h>

#define NEG9 (-1e9f)

typedef __attribute__((ext_vector_type(8))) short short8;
typedef __attribute__((ext_vector_type(8))) unsigned short ushort8;
typedef __attribute__((ext_vector_type(4))) unsigned short ushort4_t;
typedef __attribute__((ext_vector_type(4))) float f32x4;

#define MFMA_BF16(a,b,c) __builtin_amdgcn_mfma_f32_16x16x32_bf16((a),(b),(c),0,0,0)

__device__ __forceinline__ unsigned short f2bf(float f) {
  union { float f; unsigned int u; } x; x.f = f;
  unsigned int r = x.u + 0x7fffu + ((x.u >> 16) & 1u);
  return (unsigned short)(r >> 16);
}
__device__ __forceinline__ float bf2f(unsigned short h) {
  union { unsigned int u; float f; } x; x.u = ((unsigned int)h) << 16;
  return x.f;
}
__device__ __forceinline__ void gload_lds16(const unsigned short* g, unsigned short* l) {
  __builtin_amdgcn_global_load_lds(
      (const __attribute__((address_space(1))) unsigned int*)g,
      (__attribute__((address_space(3))) unsigned int*)l, 16, 0, 0);
}

// ---------------- fp32 -> bf16 convert ----------------
__global__ void cvt_f32_bf16(const float* __restrict__ in, unsigned short* __restrict__ out, int n4) {
  int i = blockIdx.x * blockDim.x + threadIdx.x;
  int stride = gridDim.x * blockDim.x;
  for (; i < n4; i += stride) {
    float4 v = ((const float4*)in)[i];
    ushort4_t o;
    o.x = f2bf(v.x); o.y = f2bf(v.y); o.z = f2bf(v.z); o.w = f2bf(v.w);
    ((ushort4_t*)out)[i] = o;
  }
}

__global__ void cvt_w6(const float* a0, const float* a1, const float* a2,
                       const float* a3, const float* a4, const float* a5,
                       unsigned short* b0, unsigned short* b1, unsigned short* b2,
                       unsigned short* b3, unsigned short* b4, unsigned short* b5) {
  const float* in; unsigned short* out;
  switch (blockIdx.y) {
    case 0: in = a0; out = b0; break;
    case 1: in = a1; out = b1; break;
    case 2: in = a2; out = b2; break;
    case 3: in = a3; out = b3; break;
    case 4: in = a4; out = b4; break;
    default: in = a5; out = b5; break;
  }
  const int n4 = 262144;
  int i = blockIdx.x * blockDim.x + threadIdx.x;
  int stride = gridDim.x * blockDim.x;
  for (; i < n4; i += stride) {
    float4 v = ((const float4*)in)[i];
    ushort4_t o;
    o.x = f2bf(v.x); o.y = f2bf(v.y); o.z = f2bf(v.z); o.w = f2bf(v.w);
    ((ushort4_t*)out)[i] = o;
  }
}

// =======================================================================
// 2-phase-per-K-tile 256x128 GEMM, BK=64, 512 threads (8 waves 2Mx4N),
// dbuf LDS 96KiB, counted vmcnt, both-sides st-swizzle.
// C[M,N] = A[M,K] @ W[N,K]^T + bias.
// MODE 0: bf16 out. MODE 1: fp32 out. MODE 2: QKV demux.
// Requires M%256==0, N%128==0, K%64==0, nwg%8==0.
// QKV: nwg=768 (3.0/CU balanced). Wo: nwg=256 (1.0/CU full).
// =======================================================================
// stage one 128x64 half-tile: linear LDS dest, source pre-swizzled byte^=(row&7)<<4
__device__ __forceinline__ void stage_half(const unsigned short* __restrict__ g, int ldg,
                                           unsigned short* lh, int t) {
#pragma unroll
  for (int j = 0; j < 2; j++) {
    int idx = j*512 + t;
    int rowh = idx >> 3;
    int colb = (idx & 7) << 4;
    int scol = colb ^ ((rowh & 7) << 4);
    gload_lds16(g + (long)rowh*ldg + (scol >> 1), lh + idx*8);
  }
}

template<int MODE>
__global__ __launch_bounds__(512, 2)
void gemm8(const unsigned short* __restrict__ A,
           const unsigned short* __restrict__ W,
           const float* __restrict__ b0, const float* __restrict__ b1,
           const float* __restrict__ b2,
           void* __restrict__ o0, void* __restrict__ o1, void* __restrict__ o2,
           int M, int N, int K) {
  __shared__ unsigned short lds[2][24576];  // per buf: A[0..16383] (256x64), B[16384..24575] (128x64)
  const int t = threadIdx.x;
  const int lane = t & 63;
  const int w = t >> 6;
  const int wm = w >> 2, wn = w & 3;        // 2 waves in M x 4 in N; per-wave 128x32
  const int lr = lane & 15, lp = lane >> 4;

  const int nbn = N >> 7;
  const int nwg = (M >> 8) * nbn;
  int bid = blockIdx.x;
  { int q = nwg >> 3; bid = (bid & 7) * q + (bid >> 3); }  // nwg%8==0 for our shapes
  const int bm = bid / nbn, bn = bid % nbn;
  const long rowA0 = (long)bm << 8;
  const long rowB0 = (long)bn << 7;
  const int KT = K >> 6;

  // prologue: B(0), A(0)h0, A(0)h1, B(1)  (8 loads/thread when KT>1)
  stage_half(W + rowB0*K,         K, &lds[0][16384], t);
  stage_half(A + rowA0*K,         K, &lds[0][0],     t);
  stage_half(A + (rowA0+128)*K,   K, &lds[0][8192],  t);
  if (KT > 1) {
    stage_half(W + rowB0*K + 64,  K, &lds[1][16384], t);
    asm volatile("s_waitcnt vmcnt(2)" ::: "memory");
  } else {
    asm volatile("s_waitcnt vmcnt(0)" ::: "memory");
  }
  __builtin_amdgcn_s_barrier();

  f32x4 acc[8][2];
#pragma unroll
  for (int m = 0; m < 8; m++)
#pragma unroll
    for (int n = 0; n < 2; n++) acc[m][n] = f32x4{0.f,0.f,0.f,0.f};

  short8 af[4][2], bf[2][2];

  for (int kt = 0; kt < KT; ++kt) {
    const int cur = kt & 1;
    const char* As = (const char*)&lds[cur][0];
    const char* Bs = (const char*)&lds[cur][16384];

    // ---- phase 0: read A rows 0..63 of wave-half (8 ds) + all B (4 ds);
    //              stage A(kt+1) h0+h1 -> buf^1; mfma 16 into acc[0..3][*]
#pragma unroll
    for (int mr = 0; mr < 4; mr++) {
      int row = wm*128 + mr*16 + lr;
      int sw = (row & 7) << 4;
#pragma unroll
      for (int kk = 0; kk < 2; kk++)
        af[mr][kk] = *(const short8*)(As + row*128 + ((kk*64 + lp*16) ^ sw));
    }
#pragma unroll
    for (int nr = 0; nr < 2; nr++) {
      int row = wn*32 + nr*16 + lr;
      int sw = (row & 7) << 4;
#pragma unroll
      for (int kk = 0; kk < 2; kk++)
        bf[nr][kk] = *(const short8*)(Bs + row*128 + ((kk*64 + lp*16) ^ sw));
    }
    if (kt+1 < KT) {
      stage_half(A + rowA0*K + (kt+1)*64,         K, &lds[cur^1][0],    t);
      stage_half(A + (rowA0+128)*K + (kt+1)*64,   K, &lds[cur^1][8192], t);
    }
    __builtin_amdgcn_s_barrier();
    __builtin_amdgcn_s_setprio(1);
#pragma unroll
    for (int mr = 0; mr < 4; mr++)
#pragma unroll
      for (int nr = 0; nr < 2; nr++)
#pragma unroll
        for (int kk = 0; kk < 2; kk++)
          acc[mr][nr] = MFMA_BF16(af[mr][kk], bf[nr][kk], acc[mr][nr]);
    __builtin_amdgcn_s_setprio(0);
    __builtin_amdgcn_s_barrier();

    // ---- phase 1: read A rows 64..127 (8 ds); stage B(kt+2) -> own-buf B
    //              (B(cur) reads all completed before ph0 MFMA barrier); mfma 16
#pragma unroll
    for (int mr = 0; mr < 4; mr++) {
      int row = wm*128 + 64 + mr*16 + lr;
      int sw = (row & 7) << 4;
#pragma unroll
      for (int kk = 0; kk < 2; kk++)
        af[mr][kk] = *(const short8*)(As + row*128 + ((kk*64 + lp*16) ^ sw));
    }
    if (kt+2 < KT) stage_half(W + rowB0*K + (kt+2)*64, K, &lds[cur][16384], t);
    __builtin_amdgcn_s_barrier();
    __builtin_amdgcn_s_setprio(1);
#pragma unroll
    for (int mr = 0; mr < 4; mr++)
#pragma unroll
      for (int nr = 0; nr < 2; nr++)
#pragma unroll
        for (int kk = 0; kk < 2; kk++)
          acc[4+mr][nr] = MFMA_BF16(af[mr][kk], bf[nr][kk], acc[4+mr][nr]);
    __builtin_amdgcn_s_setprio(0);
    // counted vmcnt: leftover B(kt+1)<=2 + A(kt+1) 4 + B(kt+2) 2 outstanding;
    // need B(kt+1)+A(kt+1) done -> vmcnt(2); drain fully at KT-2.
    if (kt+1 < KT) {
      if (kt+2 < KT) { asm volatile("s_waitcnt vmcnt(2)" ::: "memory"); }
      else           { asm volatile("s_waitcnt vmcnt(0)" ::: "memory"); }
    }
    __builtin_amdgcn_s_barrier();
  }

  // ---- epilogue: per-wave 128x32
  if (MODE == 2) {
    const int which = (int)(rowB0 >> 10);
    unsigned short* Co = which==0 ? (unsigned short*)o0 : which==1 ? (unsigned short*)o1 : (unsigned short*)o2;
    const float* bb = which==0 ? b0 : which==1 ? b1 : b2;
    const long colbase = rowB0 - (long)which*1024;
#pragma unroll
    for (int m = 0; m < 8; m++)
#pragma unroll
      for (int n = 0; n < 2; n++) {
        long row = rowA0 + wm*128 + m*16 + lp*4;
        long col = colbase + wn*32 + n*16 + lr;
        float bv = bb[col];
#pragma unroll
        for (int r = 0; r < 4; r++)
          Co[(row + r)*1024 + col] = f2bf(acc[m][n][r] + bv);
      }
  } else {
#pragma unroll
    for (int m = 0; m < 8; m++)
#pragma unroll
      for (int n = 0; n < 2; n++) {
        long row = rowA0 + wm*128 + m*16 + lp*4;
        long col = rowB0 + wn*32 + n*16 + lr;
        float bv = b0[col];
#pragma unroll
        for (int r = 0; r < 4; r++) {
          float v = acc[m][n][r] + bv;
          if (MODE == 1) ((float*)o0)[(row + r)*N + col] = v;
          else ((unsigned short*)o0)[(row + r)*N + col] = f2bf(v);
        }
      }
  }
}

// ---------------- m97-style 128^2 GEMM (kept for the small r/h projection) ----------------
template<int OUT_F32>
__global__ __launch_bounds__(256)
void gemm_bt(const unsigned short* __restrict__ A,
             const unsigned short* __restrict__ W,
             const float* __restrict__ bias,
             void* __restrict__ Cout,
             int M, int N, int K) {
  __shared__ unsigned short As[128*32];
  __shared__ unsigned short Bs[128*32];
  const int t = threadIdx.x;
  const int lane = t & 63;
  const int wave = t >> 6;
  const int wr = wave >> 1, wc = wave & 1;
  const int lr = lane & 15;
  const int lk = (lane >> 4) << 3;

  const int nbn = N >> 7;
  const int nwg = (M >> 7) * nbn;
  int bid = blockIdx.x;
  if ((nwg & 7) == 0) { int q = nwg >> 3; bid = (bid & 7) * q + (bid >> 3); }
  const int bm = bid / nbn, bn = bid % nbn;

  const long rowA0 = (long)bm * 128;
  const long rowB0 = (long)bn * 128;
  const int srow = t >> 2;
  const int scol = (t & 3) << 3;

  f32x4 acc[4][4];
#pragma unroll
  for (int m = 0; m < 4; m++)
#pragma unroll
    for (int n = 0; n < 4; n++) acc[m][n] = f32x4{0.f,0.f,0.f,0.f};

  for (int k0 = 0; k0 < K; k0 += 32) {
    const unsigned short* ga = A + (rowA0 + srow) * K + k0 + scol;
    const unsigned short* gb = W + (rowB0 + srow) * K + k0 + scol;
    gload_lds16(ga,              As + t*8);
    gload_lds16(ga + (long)64*K, As + t*8 + 2048);
    gload_lds16(gb,              Bs + t*8);
    gload_lds16(gb + (long)64*K, Bs + t*8 + 2048);
    __syncthreads();
    short8 af[4], bf[4];
#pragma unroll
    for (int m = 0; m < 4; m++) af[m] = *(const short8*)&As[(wr*64 + m*16 + lr)*32 + lk];
#pragma unroll
    for (int n = 0; n < 4; n++) bf[n] = *(const short8*)&Bs[(wc*64 + n*16 + lr)*32 + lk];
#pragma unroll
    for (int m = 0; m < 4; m++)
#pragma unroll
      for (int n = 0; n < 4; n++)
        acc[m][n] = MFMA_BF16(af[m], bf[n], acc[m][n]);
    __syncthreads();
  }

  const int rg4 = (lane >> 4) * 4;
#pragma unroll
  for (int m = 0; m < 4; m++) {
#pragma unroll
    for (int n = 0; n < 4; n++) {
      long row = rowA0 + wr*64 + m*16 + rg4;
      long col = rowB0 + wc*64 + n*16 + lr;
      float bv = bias[col];
#pragma unroll
      for (int r = 0; r < 4; r++) {
        float v = acc[m][n][r] + bv;
        if (OUT_F32) ((float*)Cout)[(row + r) * N + col] = v;
        else ((unsigned short*)Cout)[(row + r) * N + col] = f2bf(v);
      }
    }
  }
}

// ---------------- chunk_repr gather + pad to 128 rows; also stack r/h bias ----------------
__global__ void repr_pad(const float* __restrict__ hs, unsigned short* __restrict__ out,
                         const float* __restrict__ br, const float* __restrict__ bh,
                         float* __restrict__ brh) {
  int r = blockIdx.x;
  int t = threadIdx.x;
  long base = (long)r * 1024;
  if (r < 64) {
    int b = r >> 5, c = r & 31;
    const float* src = hs + ((long)(b*4096 + c*128 + 127)) * 1024;
#pragma unroll
    for (int j = 0; j < 4; j++) { int idx = t + j*256; out[base + idx] = f2bf(src[idx]); }
  } else {
#pragma unroll
    for (int j = 0; j < 4; j++) out[base + t + j*256] = 0;
    if (r == 64) {
#pragma unroll
      for (int j = 0; j < 4; j++) { int idx = t + j*256; brh[idx] = br[idx]; }
    } else if (r == 65) {
#pragma unroll
      for (int j = 0; j < 4; j++) { int idx = t + j*256; brh[1024 + idx] = bh[idx]; }
    }
  }
}

// ---------------- chunk scores + softmax -> probs [B,H,32,32] fp32 ----------------
__global__ __launch_bounds__(1024) void chunk_probs_k(
    const unsigned short* __restrict__ rbh,
    float* __restrict__ probs) {
  __shared__ float rt[32][65];
  __shared__ float ht[32][65];
  int h = blockIdx.x, b = blockIdx.y;
  int t = threadIdx.x;
#pragma unroll
  for (int j = 0; j < 2; j++) {
    int idx = t + j*1024;
    int c = idx >> 6, d = idx & 63;
    rt[c][d] = bf2f(rbh[(long)(b*32 + c)*2048 + h*64 + d]);
    ht[c][d] = bf2f(rbh[(long)(b*32 + c)*2048 + 1024 + h*64 + d]);
  }
  __syncthreads();
  int e = t & 31, c = t >> 5;
  float s = 0.f;
#pragma unroll
  for (int d = 0; d < 64; d++) s += rt[c][d] * ht[e][d];
  s *= 0.125f;
  if (e < c) s = NEG9;
  float m = s;
#pragma unroll
  for (int off = 16; off > 0; off >>= 1) m = fmaxf(m, __shfl_xor(m, off, 32));
  float p = __expf(s - m);
  float sum = p;
#pragma unroll
  for (int off = 16; off > 0; off >>= 1) sum += __shfl_xor(sum, off, 32);
  probs[(((long)(b*16 + h))*32 + c)*32 + e] = p / sum;
}

// ---------------- F^T = V^T K per chunk via MFMA: fbuf[bid][e*64+d] ----------------
__global__ __launch_bounds__(256) void f_kernel(
    const unsigned short* __restrict__ Kb, const unsigned short* __restrict__ Vb,
    unsigned short* __restrict__ f) {
  __shared__ unsigned short vT[64*136];
  __shared__ unsigned short kT[64*136];
  int bid = blockIdx.x;
  int c = bid & 31, h = (bid >> 5) & 15, b = bid >> 9;
  int t = threadIdx.x;
  const unsigned short* kg = Kb + ((long)(b*4096 + c*128))*1024 + h*64;
  const unsigned short* vg = Vb + ((long)(b*4096 + c*128))*1024 + h*64;
  {
    int eq = t & 7, sq = t >> 3;
    int s0 = sq*4, e0 = eq*8;
    ushort8 v[4], k[4];
#pragma unroll
    for (int r = 0; r < 4; r++) {
      v[r] = *(const ushort8*)&vg[(long)(s0 + r)*1024 + e0];
      k[r] = *(const ushort8*)&kg[(long)(s0 + r)*1024 + e0];
    }
#pragma unroll
    for (int x = 0; x < 8; x++) {
      ushort4_t pv, pk;
      pv.x = v[0][x]; pv.y = v[1][x]; pv.z = v[2][x]; pv.w = v[3][x];
      pk.x = k[0][x]; pk.y = k[1][x]; pk.z = k[2][x]; pk.w = k[3][x];
      *(ushort4_t*)&vT[(e0 + x)*136 + s0] = pv;
      *(ushort4_t*)&kT[(e0 + x)*136 + s0] = pk;
    }
  }
  __syncthreads();
  const int lane = t & 63, w = t >> 6;
  const int lr = lane & 15, lk = (lane >> 4) << 3;
  const int rg4 = (lane >> 4) * 4;
  const int e0w = (w & 1) * 32, d0w = (w >> 1) * 32;

  f32x4 acc[2][2];
#pragma unroll
  for (int m = 0; m < 2; m++)
#pragma unroll
    for (int n = 0; n < 2; n++) acc[m][n] = f32x4{0.f,0.f,0.f,0.f};
#pragma unroll
  for (int kk = 0; kk < 4; kk++) {
    short8 af[2], bf[2];
#pragma unroll
    for (int m = 0; m < 2; m++) af[m] = *(const short8*)&vT[(e0w + m*16 + lr)*136 + kk*32 + lk];
#pragma unroll
    for (int n = 0; n < 2; n++) bf[n] = *(const short8*)&kT[(d0w + n*16 + lr)*136 + kk*32 + lk];
#pragma unroll
    for (int m = 0; m < 2; m++)
#pragma unroll
      for (int n = 0; n < 2; n++) acc[m][n] = MFMA_BF16(af[m], bf[n], acc[m][n]);
  }
  unsigned short* fo = f + (long)bid * 4096;
#pragma unroll
  for (int m = 0; m < 2; m++)
#pragma unroll
    for (int n = 0; n < 2; n++)
#pragma unroll
      for (int r = 0; r < 4; r++)
        fo[(e0w + m*16 + rg4 + r)*64 + d0w + n*16 + lr] = f2bf(acc[m][n][r]);
}

// ---------------- retrieved^T ----------------
__global__ __launch_bounds__(256) void retrieve_k(
    const float* __restrict__ probs, const unsigned short* __restrict__ f,
    unsigned short* __restrict__ retT) {
  __shared__ float PL[1024];
  int bh = blockIdx.x;
  int xt = blockIdx.y;
  int t = threadIdx.x;
  *(float4*)&PL[t*4] = *(const float4*)&probs[(long)bh*1024 + t*4];
  __syncthreads();
  const unsigned int* fb = (const unsigned int*)(f + (long)bh*32*4096);
  const int xo = xt*256 + t;
  unsigned int fv[32];
#pragma unroll
  for (int ec = 0; ec < 32; ec++) fv[ec] = fb[ec*2048 + xo];
  unsigned int* ro = (unsigned int*)retT + (long)bh*32*2048 + xo;
  for (int c = 0; c < 32; c++) {
    float a0 = 0.f, a1 = 0.f;
#pragma unroll
    for (int e4 = 0; e4 < 8; e4++) {
      float4 p = *(const float4*)&PL[c*32 + e4*4];
#pragma unroll
      for (int j = 0; j < 4; j++) {
        unsigned int v = fv[e4*4 + j];
        union { unsigned int u; float ff; } lo, hi;
        lo.u = v << 16; hi.u = v & 0xffff0000u;
        a0 += p[j] * lo.ff;
        a1 += p[j] * hi.ff;
      }
    }
    ro[(long)c*2048] = (unsigned int)f2bf(a0) | ((unsigned int)f2bf(a1) << 16);
  }
}

// ---------------- fused attention per (b,h,c) ----------------
__global__ __launch_bounds__(256) void attn_k(
    const unsigned short* __restrict__ Qb,
    const unsigned short* __restrict__ Kb,
    const unsigned short* __restrict__ Vb,
    const unsigned short* __restrict__ retT,
    unsigned short* __restrict__ attn) {
  __shared__ unsigned short ks[128*64];
  __shared__ unsigned short vT[64*136];
  __shared__ unsigned short rT[64*64];
  __shared__ unsigned short P[128*136];
  const int bid = blockIdx.x;
  const int c = bid & 31, h = (bid >> 5) & 15, b = bid >> 9;
  const int t = threadIdx.x;
  const int lane = t & 63, w = t >> 6;
  const int lr = lane & 15, lk = (lane >> 4) << 3;
  const int rg4 = (lane >> 4) * 4;

  const long rowbase = (long)(b*4096 + c*128);
  const unsigned short* kg = Kb + rowbase*1024 + h*64;
  const unsigned short* vg = Vb + rowbase*1024 + h*64;
  const unsigned short* qg = Qb + rowbase*1024 + h*64;
  const unsigned short* rtg = retT + (long)bid*4096;

  {
    const int off = (t & 7) << 4;
#pragma unroll
    for (int i = 0; i < 4; i++) {
      int row = (t >> 3) + i*32;
      int srcoff = off ^ ((row & 7) << 4);
      gload_lds16(kg + (long)row*1024 + (srcoff >> 1), ks + t*8 + i*2048);
    }
#pragma unroll
    for (int i = 0; i < 2; i++) {
      int row = ((t + i*256) >> 3);
      int srcoff = off ^ ((row & 7) << 4);
      gload_lds16(rtg + (long)row*64 + (srcoff >> 1), rT + (t + i*256)*8);
    }
  }
  {
    int eq = t & 7, sq = t >> 3;
    int s0 = sq*4, e0 = eq*8;
    ushort8 v[4];
#pragma unroll
    for (int r = 0; r < 4; r++) v[r] = *(const ushort8*)&vg[(long)(s0 + r)*1024 + e0];
#pragma unroll
    for (int x = 0; x < 8; x++) {
      ushort4_t pv;
      pv.x = v[0][x]; pv.y = v[1][x]; pv.z = v[2][x]; pv.w = v[3][x];
      *(ushort4_t*)&vT[(e0 + x)*136 + s0] = pv;
    }
  }
  __syncthreads();

  short8 qa[2][2];
#pragma unroll
  for (int m = 0; m < 2; m++)
#pragma unroll
    for (int kk = 0; kk < 2; kk++)
      qa[m][kk] = *(const short8*)&qg[(long)(w*32 + m*16 + lr)*1024 + kk*32 + lk];
  f32x4 scf[2][8];
#pragma unroll
  for (int m = 0; m < 2; m++)
#pragma unroll
    for (int n = 0; n < 8; n++) scf[m][n] = f32x4{0.f,0.f,0.f,0.f};
#pragma unroll
  for (int n = 0; n < 8; n++) {
    const int krow = n*16 + lr;
    const int swzmask = (krow & 7) << 4;
#pragma unroll
    for (int kk = 0; kk < 2; kk++) {
      int colb = (kk*64 + ((lane >> 4) << 4)) ^ swzmask;
      short8 kf = *(const short8*)&ks[krow*64 + (colb >> 1)];
#pragma unroll
      for (int m = 0; m < 2; m++) scf[m][n] = MFMA_BF16(qa[m][kk], kf, scf[m][n]);
    }
  }

  float rsum[2][4];
#pragma unroll
  for (int m = 0; m < 2; m++) {
#pragma unroll
    for (int r = 0; r < 4; r++) {
      int srow = w*32 + m*16 + rg4 + r;
      float vals[8];
      float mx = -1e30f;
#pragma unroll
      for (int n = 0; n < 8; n++) {
        int tcol = n*16 + lr;
        float v_ = scf[m][n][r] * 0.125f;
        if (tcol < srow) v_ = NEG9;
        vals[n] = v_;
        mx = fmaxf(mx, v_);
      }
#pragma unroll
      for (int off = 1; off < 16; off <<= 1) mx = fmaxf(mx, __shfl_xor(mx, off, 16));
      float sum = 0.f;
#pragma unroll
      for (int n = 0; n < 8; n++) {
        float p = __expf(vals[n] - mx);
        sum += p;
        P[srow*136 + n*16 + lr] = f2bf(p);
      }
#pragma unroll
      for (int off = 1; off < 16; off <<= 1) sum += __shfl_xor(sum, off, 16);
      rsum[m][r] = sum;
    }
  }

  f32x4 outa[2][4];
#pragma unroll
  for (int m = 0; m < 2; m++)
#pragma unroll
    for (int n = 0; n < 4; n++) outa[m][n] = f32x4{0.f,0.f,0.f,0.f};
#pragma unroll
  for (int n = 0; n < 4; n++) {
    const int rrow = n*16 + lr;
    const int swzmask = (rrow & 7) << 4;
#pragma unroll
    for (int kk = 0; kk < 2; kk++) {
      int colb = (kk*64 + ((lane >> 4) << 4)) ^ swzmask;
      short8 rf = *(const short8*)&rT[rrow*64 + (colb >> 1)];
#pragma unroll
      for (int m = 0; m < 2; m++) outa[m][n] = MFMA_BF16(qa[m][kk], rf, outa[m][n]);
    }
  }

  f32x4 pv[2][4];
#pragma unroll
  for (int m = 0; m < 2; m++)
#pragma unroll
    for (int n = 0; n < 4; n++) pv[m][n] = f32x4{0.f,0.f,0.f,0.f};
#pragma unroll
  for (int kk = 0; kk < 4; kk++) {
    short8 pa[2];
#pragma unroll
    for (int m = 0; m < 2; m++) pa[m] = *(const short8*)&P[(w*32 + m*16 + lr)*136 + kk*32 + lk];
#pragma unroll
    for (int n = 0; n < 4; n++) {
      short8 vf = *(const short8*)&vT[(n*16 + lr)*136 + kk*32 + lk];
#pragma unroll
      for (int m = 0; m < 2; m++) pv[m][n] = MFMA_BF16(pa[m], vf, pv[m][n]);
    }
  }

  unsigned short* ao = attn + rowbase*1024 + h*64;
#pragma unroll
  for (int m = 0; m < 2; m++)
#pragma unroll
    for (int n = 0; n < 4; n++)
#pragma unroll
      for (int r = 0; r < 4; r++) {
        int srow = w*32 + m*16 + rg4 + r;
        float v_ = pv[m][n][r] / rsum[m][r] + outa[m][n][r];
        ao[(long)srow*1024 + n*16 + lr] = f2bf(v_);
      }
}

// ---------------- launch ----------------
extern "C" void kernel_launch(void* const* d_in, const int* in_sizes, int n_in,
                              void* d_out, int out_size, void* d_ws, size_t ws_size,
                              hipStream_t stream) {
  const float* hs = (const float*)d_in[0];
  const float* Wq = (const float*)d_in[1];
  const float* bq = (const float*)d_in[2];
  const float* Wk = (const float*)d_in[3];
  const float* bk = (const float*)d_in[4];
  const float* Wv = (const float*)d_in[5];
  const float* bv = (const float*)d_in[6];
  const float* Wo = (const float*)d_in[7];
  const float* bo = (const float*)d_in[8];
  const float* Wr = (const float*)d_in[9];
  const float* br = (const float*)d_in[10];
  const float* Wh = (const float*)d_in[11];
  const float* bh = (const float*)d_in[12];

  char* p = (char*)d_ws;
  unsigned short* hsb  = (unsigned short*)p; p += (size_t)8192*1024*2;
  unsigned short* Wqkv = (unsigned short*)p; p += (size_t)3072*1024*2;
  unsigned short* Wob  = (unsigned short*)p; p += (size_t)1024*1024*2;
  unsigned short* Wrh  = (unsigned short*)p; p += (size_t)2048*1024*2;
  unsigned short* Qb   = (unsigned short*)p; p += (size_t)8192*1024*2;
  unsigned short* Kb   = (unsigned short*)p; p += (size_t)8192*1024*2;
  unsigned short* Vb   = (unsigned short*)p; p += (size_t)8192*1024*2;
  unsigned short* reprb= (unsigned short*)p; p += (size_t)128*1024*2;
  unsigned short* rbhb = (unsigned short*)p; p += (size_t)128*2048*2;
  float*          brh  = (float*)p;          p += (size_t)2048*4;
  float*          probs= (float*)p;          p += (size_t)2*16*32*32*4;
  unsigned short* fbuf = (unsigned short*)p; p += (size_t)2*16*32*4096*2;
  unsigned short* retT = (unsigned short*)p; p += (size_t)2*16*32*4096*2;
  unsigned short* attnb = hsb;  // overlay: hsb dead after QKV+r/h GEMMs

  cvt_f32_bf16<<<8192, 256, 0, stream>>>(hs, hsb, 2097152);
  cvt_w6<<<dim3(256, 6), 256, 0, stream>>>(Wq, Wk, Wv, Wo, Wr, Wh,
                                           Wqkv, Wqkv + (size_t)1024*1024,
                                           Wqkv + (size_t)2048*1024,
                                           Wob, Wrh, Wrh + (size_t)1024*1024);
  repr_pad<<<128, 256, 0, stream>>>(hs, reprb, br, bh, brh);

  // fused QKV projection (256x128 tiles, 768 WGs = 3.0/CU balanced)
  gemm8<2><<<768, 512, 0, stream>>>(hsb, Wqkv, bq, bk, bv, Qb, Kb, Vb, 8192, 3072, 1024);

  // fused r/h projection (small M -> 128^2 kernel)
  gemm_bt<0><<<16, 256, 0, stream>>>(reprb, Wrh, brh, rbhb, 128, 2048, 1024);

  chunk_probs_k<<<dim3(16, 2), 1024, 0, stream>>>(rbhb, probs);
  f_kernel<<<1024, 256, 0, stream>>>(Kb, Vb, fbuf);
  retrieve_k<<<dim3(32, 8), 256, 0, stream>>>(probs, fbuf, retT);
  attn_k<<<1024, 256, 0, stream>>>(Qb, Kb, Vb, retT, attnb);

  // output projection (256x128 tiles, 256 WGs = 1.0/CU full GPU, fp32 out)
  gemm8<1><<<256, 512, 0, stream>>>(attnb, Wob, bo, nullptr, nullptr,
                                    d_out, nullptr, nullptr, 8192, 1024, 1024);
}